// Round 1
// baseline (982.488 us; speedup 1.0000x reference)
//
#include <hip/hip_runtime.h>
#include <hip/hip_bf16.h>
#include <cstdint>

// ---------------------------------------------------------------------------
// ThreeLayerCNN (BranchyNet early-exit), B=4096.
// Precision: conv1/conv2/exit1/exit2 fp32 (argmax parity with numpy ref);
// big FC GEMMs (l1c1, l1c2) bf16 MFMA w/ fp32 accum (output tol 0.146).
// Round 12:
//  - conv2 rework: 2 images/block, 10 oc/thread (125 thr/img = 5 ocg x 25 pos),
//    weights read DIRECT from global (L1/L2-resident; wbuf staging removed),
//    input-only LDS dbuf (5-ic chunks, exactly 10 chunks, issue-early/
//    write-late staging). Per-output FP expression tree UNCHANGED
//    (ic order 0..49 sequential, verbatim 9-term tap expression) ->
//    h2 bit-identical -> exit2 argmax parity preserved.
//  - k_stage1 LDS 24832 -> 15488 B; grid 8704 -> 6656; launch_bounds(256,4).
// ---------------------------------------------------------------------------

typedef __bf16 bf16_t;
typedef __bf16 bf16x8 __attribute__((ext_vector_type(8)));
typedef float  f32x4  __attribute__((ext_vector_type(4)));

#define B_IMG 4096

// ======================= role bodies (device functions) =====================

__device__ void role_conv1(char* smem, int blk,
    const float* __restrict__ x, const float* __restrict__ w1,
    const float* __restrict__ b1, float* __restrict__ h1)
{
    float* ws = (float*)smem;        // 450
    float* bs = ws + 456;            // 50
    const int t = threadIdx.x;
    for (int i = t; i < 450; i += 256) ws[i] = w1[i];
    if (t < 50) bs[t] = b1[t];
    __syncthreads();

    const int idx = blk * 256 + t;
    if (idx >= B_IMG * 169) return;
    const int b   = idx / 169;
    const int pos = idx % 169;
    const int py = pos / 13, px = pos % 13;

    const float* xp = x + (size_t)b * 784 + (2 * py) * 28 + 2 * px;
    float p[4][4];
#pragma unroll
    for (int r = 0; r < 4; ++r)
#pragma unroll
        for (int c = 0; c < 4; ++c) p[r][c] = xp[r * 28 + c];

    float* hb = h1 + (size_t)b * 8480 + pos;
    if (pos < 30) h1[(size_t)b * 8480 + 8450 + pos] = 0.f;   // zero pad cols

    for (int oc = 0; oc < 50; ++oc) {
        const float* wp = &ws[oc * 9];
        const float w00 = wp[0], w01 = wp[1], w02 = wp[2];
        const float w10 = wp[3], w11 = wp[4], w12 = wp[5];
        const float w20 = wp[6], w21 = wp[7], w22 = wp[8];
        float a[2][2];
#pragma unroll
        for (int dy = 0; dy < 2; ++dy)
#pragma unroll
            for (int dx = 0; dx < 2; ++dx) {
                a[dy][dx] = p[dy + 0][dx + 0] * w00 + p[dy + 0][dx + 1] * w01 + p[dy + 0][dx + 2] * w02
                          + p[dy + 1][dx + 0] * w10 + p[dy + 1][dx + 1] * w11 + p[dy + 1][dx + 2] * w12
                          + p[dy + 2][dx + 0] * w20 + p[dy + 2][dx + 1] * w21 + p[dy + 2][dx + 2] * w22;
            }
        float v = fmaxf(fmaxf(a[0][0], a[0][1]), fmaxf(a[1][0], a[1][1])) + bs[oc];
        hb[oc * 169] = fmaxf(v, 0.f);
    }
}

__device__ void role_wb16(int blk, const float* __restrict__ src,
                          bf16_t* __restrict__ dst, int N, int K, int Kp, int total)
{
    const int idx = blk * 256 + threadIdx.x;
    if (idx >= total) return;
    const int n = idx / Kp, k = idx % Kp;
    const float v = (n < N && k < K) ? src[(size_t)n * K + k] : 0.f;
    dst[idx] = (bf16_t)v;
}

__device__ void role_w2t(int blk, const float* __restrict__ w2, float* __restrict__ w2p)
{
    const int idx = blk * 256 + threadIdx.x;
    if (idx >= 50 * 600) return;
    const int ic = idx / 600, r = idx % 600, oc = r / 12, j = r % 12;
    w2p[idx] = (j < 9) ? w2[oc * 450 + ic * 9 + j] : 0.f;
}

// conv2 (50->50) + relu + pool, Round-12 structure:
//   2 images per block; thread = 10 oc x 1 pooled pos (125 thr/img, t<250).
//   Input: LDS double-buffered 5-ic chunks (in[2][2 img][845] = 13520 B),
//   staged issue-early/write-late. Weights: direct global reads (w2p is
//   120 KB, L2-resident; <=3 distinct 16B lines per wave per load).
//   FP expression tree per output identical to r8..r11 (ic order 0..49,
//   verbatim tap expression) -> exit2 argmax parity.
__device__ void role_conv2(char* smem, int blkpair,
    const float* __restrict__ h1, const float* __restrict__ w2p,
    const float* __restrict__ b2, float* __restrict__ h2)
{
    float* in = (float*)smem;            // [2][1690]  (2 img x 845 per chunk)
    const int t  = threadIdx.x;
    const int b0 = blkpair * 2;

    // stage chunk 0 (ic 0..4, both images)
    for (int s = t; s < 1690; s += 256) {
        const int img = (s >= 845);
        const int off = s - img * 845;
        in[s] = h1[(size_t)(b0 + img) * 8480 + off];
    }
    __syncthreads();
    if (t < 60) {
        const int img = t / 30, o = t - img * 30;
        h2[(size_t)(b0 + img) * 1280 + 1250 + o] = 0.f;      // zero pad cols
    }

    const int il  = t / 125;             // image 0/1
    const int tl  = t - il * 125;
    const int ocg = tl / 25;             // 0..4
    const int pos = tl - ocg * 25;
    const int py = pos / 5, px = pos - py * 5;
    const int oc0 = ocg * 10;
    const bool act = (t < 250);

    float acc[10][4];
#pragma unroll
    for (int j = 0; j < 10; ++j)
#pragma unroll
        for (int q = 0; q < 4; ++q) acc[j][q] = 0.f;

    const float* ib0 = in + il * 845 + (2 * py) * 13 + 2 * px;
    const float* wb0 = w2p + oc0 * 12;

    for (int c = 0; c < 10; ++c) {       // 10 chunks x 5 ic = ic 0..49 in order
        const int cur = c & 1;

        // issue next-chunk global loads early (write-late after compute)
        float stg[7];
        if (c + 1 < 10) {
            const int base = (c + 1) * 845;
#pragma unroll
            for (int u = 0; u < 7; ++u) {
                const int s = t + u * 256;
                if (s < 1690) {
                    const int img = (s >= 845);
                    const int off = s - img * 845;
                    stg[u] = h1[(size_t)(b0 + img) * 8480 + base + off];
                }
            }
        }

        if (act) {
            const float* ibc = ib0 + cur * 1690;
            const int ic0 = c * 5;
#pragma unroll 1
            for (int icl = 0; icl < 5; ++icl) {
                float p[4][4];
                const float* ip = ibc + icl * 169;
#pragma unroll
                for (int r = 0; r < 4; ++r)
#pragma unroll
                    for (int cc = 0; cc < 4; ++cc) p[r][cc] = ip[r * 13 + cc];
                const float* wl = wb0 + (size_t)(ic0 + icl) * 600;
#pragma unroll
                for (int j = 0; j < 10; ++j) {
                    const f32x4 wv0 = *(const f32x4*)(wl + j * 12);
                    const f32x4 wv1 = *(const f32x4*)(wl + j * 12 + 4);
                    const f32x4 wv2 = *(const f32x4*)(wl + j * 12 + 8);
                    const float w00 = wv0[0], w01 = wv0[1], w02 = wv0[2];
                    const float w10 = wv0[3], w11 = wv1[0], w12 = wv1[1];
                    const float w20 = wv1[2], w21 = wv1[3], w22 = wv2[0];
#pragma unroll
                    for (int dy = 0; dy < 2; ++dy)
#pragma unroll
                        for (int dx = 0; dx < 2; ++dx) {
                            acc[j][dy * 2 + dx] +=
                                  p[dy + 0][dx + 0] * w00 + p[dy + 0][dx + 1] * w01 + p[dy + 0][dx + 2] * w02
                                + p[dy + 1][dx + 0] * w10 + p[dy + 1][dx + 1] * w11 + p[dy + 1][dx + 2] * w12
                                + p[dy + 2][dx + 0] * w20 + p[dy + 2][dx + 1] * w21 + p[dy + 2][dx + 2] * w22;
                        }
                }
            }
        }

        if (c + 1 < 10) {                // write-late into the other buffer
            const int nxt = cur ^ 1;
#pragma unroll
            for (int u = 0; u < 7; ++u) {
                const int s = t + u * 256;
                if (s < 1690) in[nxt * 1690 + s] = stg[u];
            }
        }
        __syncthreads();
    }

    if (act) {
#pragma unroll
        for (int j = 0; j < 10; ++j) {
            float v = fmaxf(fmaxf(acc[j][0], acc[j][1]), fmaxf(acc[j][2], acc[j][3]));
            h2[(size_t)(b0 + il) * 1280 + (oc0 + j) * 25 + pos] = fmaxf(v + b2[oc0 + j], 0.f);
        }
    }
}

__device__ void role_conv3(char* smem, int blk,
    const float* __restrict__ h2, const float* __restrict__ w3,
    const float* __restrict__ b3, float* __restrict__ f3)
{
    float* in = (float*)smem;    // 5000
    const int t = threadIdx.x;
    for (int i = t; i < 5000; i += 256) {
        const int img = i / 1250, off = i % 1250;
        in[i] = h2[(size_t)(blk * 4 + img) * 1280 + off];
    }
    __syncthreads();
    const int il = t >> 6;
    const int oc = t & 63;
    if (oc >= 50) return;

    const float* ip0 = &in[il * 1250];
    float a00 = 0.f, a01 = 0.f, a10 = 0.f, a11 = 0.f;
    for (int ic = 0; ic < 50; ++ic) {
        float p[4][4];
        const float* ip = ip0 + ic * 25;
#pragma unroll
        for (int r = 0; r < 4; ++r)
#pragma unroll
            for (int c = 0; c < 4; ++c) p[r][c] = ip[r * 5 + c];
        const float* wp = &w3[((size_t)oc * 50 + ic) * 9];
        const float w00 = wp[0], w01 = wp[1], w02 = wp[2];
        const float w10 = wp[3], w11 = wp[4], w12 = wp[5];
        const float w20 = wp[6], w21 = wp[7], w22 = wp[8];
        a00 += p[0][0]*w00 + p[0][1]*w01 + p[0][2]*w02 + p[1][0]*w10 + p[1][1]*w11 + p[1][2]*w12 + p[2][0]*w20 + p[2][1]*w21 + p[2][2]*w22;
        a01 += p[0][1]*w00 + p[0][2]*w01 + p[0][3]*w02 + p[1][1]*w10 + p[1][2]*w11 + p[1][3]*w12 + p[2][1]*w20 + p[2][2]*w21 + p[2][3]*w22;
        a10 += p[1][0]*w00 + p[1][1]*w01 + p[1][2]*w02 + p[2][0]*w10 + p[2][1]*w11 + p[2][2]*w12 + p[3][0]*w20 + p[3][1]*w21 + p[3][2]*w22;
        a11 += p[1][1]*w00 + p[1][2]*w01 + p[1][3]*w02 + p[2][1]*w10 + p[2][2]*w11 + p[2][3]*w12 + p[3][1]*w20 + p[3][2]*w21 + p[3][3]*w22;
    }
    float v = fmaxf(fmaxf(a00, a01), fmaxf(a10, a11)) + b3[oc];
    f3[(size_t)(blk * 4 + il) * 50 + oc] = fmaxf(v, 0.f);
}

__device__ void role_exit(char* smem, int b,
    const float* __restrict__ F, int ldf, int K,
    const float* __restrict__ dw, const float* __restrict__ db, int* __restrict__ e)
{
    float* r0 = (float*)smem;   // 256
    float* r1 = r0 + 256;       // 256
    const int t = threadIdx.x;
    const float* f = F + (size_t)b * ldf;
    float s0 = 0.f, s1 = 0.f;
    for (int i = t; i < K; i += 256) {
        const float v = f[i];
        s0 += v * dw[i];
        s1 += v * dw[K + i];
    }
    r0[t] = s0; r1[t] = s1;
    __syncthreads();
    for (int s = 128; s > 0; s >>= 1) {
        if (t < s) { r0[t] += r0[t + s]; r1[t] += r1[t + s]; }
        __syncthreads();
    }
    if (t == 0) e[b] = (r0[0] + db[0] >= r1[0] + db[1]) ? 1 : 0;
}

// MFMA GEMM split-K=2 (r9-proven). g in [0,512): bx=g&31, by=(g>>5)&7, kz=g>>8.
__device__ void role_gemm(char* smem, int g,
    const float* __restrict__ A, int lda, const bf16_t* __restrict__ W,
    const float* __restrict__ bias, float* __restrict__ C0, float* __restrict__ C1,
    int Kp, int khalf, int Nout, int ldc)
{
    bf16_t* As = (bf16_t*)smem;      // 128*40
    bf16_t* Bs = As + 128 * 40;      // 64*40

    const int t = threadIdx.x;
    const int m0 = (g & 31) * 128;
    const int n0 = ((g >> 5) & 7) * 64;
    const int kz = g >> 8;
    const int kbeg = kz ? khalf : 0;
    const int kend = kz ? Kp : khalf;
    float* C = kz ? C1 : C0;

    const int wave = t >> 6;
    const int lane = t & 63;
    const int wm = (wave >> 1) * 64;
    const int wn = (wave & 1) * 32;
    const int quad = lane >> 4;
    const int lr = lane & 15;

    f32x4 acc[4][2];
#pragma unroll
    for (int i = 0; i < 4; ++i)
#pragma unroll
        for (int j = 0; j < 2; ++j) acc[i][j] = (f32x4)0.f;

    const int ar = t >> 2;
    const int ac = (t & 3) * 8;

    for (int k0 = kbeg; k0 < kend; k0 += 32) {
        __syncthreads();
#pragma unroll
        for (int h = 0; h < 2; ++h) {
            const float* ap = A + (size_t)(m0 + ar + h * 64) * lda + k0 + ac;
            const float4 f0 = *(const float4*)ap;
            const float4 f1 = *(const float4*)(ap + 4);
            bf16x8 v;
            v[0] = (bf16_t)f0.x; v[1] = (bf16_t)f0.y; v[2] = (bf16_t)f0.z; v[3] = (bf16_t)f0.w;
            v[4] = (bf16_t)f1.x; v[5] = (bf16_t)f1.y; v[6] = (bf16_t)f1.z; v[7] = (bf16_t)f1.w;
            *(bf16x8*)&As[(ar + h * 64) * 40 + ac] = v;
        }
        *(uint4*)&Bs[ar * 40 + ac] = *(const uint4*)&W[(size_t)(n0 + ar) * Kp + k0 + ac];
        __syncthreads();

        bf16x8 af[4], bfr[2];
#pragma unroll
        for (int i = 0; i < 4; ++i)
            af[i] = *(const bf16x8*)&As[(wm + i * 16 + lr) * 40 + quad * 8];
#pragma unroll
        for (int j = 0; j < 2; ++j)
            bfr[j] = *(const bf16x8*)&Bs[(wn + j * 16 + lr) * 40 + quad * 8];
#pragma unroll
        for (int i = 0; i < 4; ++i)
#pragma unroll
            for (int j = 0; j < 2; ++j)
                acc[i][j] = __builtin_amdgcn_mfma_f32_16x16x32_bf16(af[i], bfr[j], acc[i][j], 0, 0, 0);
    }

#pragma unroll
    for (int j = 0; j < 2; ++j) {
        const int n = n0 + wn + j * 16 + lr;
        const float bv = (kz == 0 && n < Nout) ? bias[n] : 0.f;
#pragma unroll
        for (int i = 0; i < 4; ++i) {
            const int mrow = m0 + wm + i * 16 + quad * 4;
#pragma unroll
            for (int r = 0; r < 4; ++r)
                C[(size_t)(mrow + r) * ldc + n] = acc[i][j][r] + bv;
        }
    }
}

// lin10: out[b,o<10] = (U[+U2]) @ W^T + bias; 16 img x 16 k-strips per block.
__device__ void role_lin10(char* smem, int blk,
    const float* __restrict__ U, const float* __restrict__ U2, int ldu,
    const float* __restrict__ W, const float* __restrict__ bias,
    float* __restrict__ out)
{
    float* red = (float*)smem;   // [16][10][17]
    const int t = threadIdx.x;
    const int ks = t & 15;
    const int il = t >> 4;
    const int b  = blk * 16 + il;
    const float* u = U + (size_t)b * ldu;

    float acc[10];
#pragma unroll
    for (int o = 0; o < 10; ++o) acc[o] = 0.f;

    if (U2) {
        const float* u2 = U2 + (size_t)b * ldu;
        for (int i = 0; i < 31; ++i) {
            const int k = ks + i * 16;
            const float uv = u[k] + u2[k];
#pragma unroll
            for (int o = 0; o < 10; ++o) acc[o] += uv * W[o * 500 + k];
        }
        const int k = ks + 496;
        if (k < 500) {
            const float uv = u[k] + u2[k];
#pragma unroll
            for (int o = 0; o < 10; ++o) acc[o] += uv * W[o * 500 + k];
        }
    } else {
        for (int i = 0; i < 31; ++i) {
            const int k = ks + i * 16;
            const float uv = u[k];
#pragma unroll
            for (int o = 0; o < 10; ++o) acc[o] += uv * W[o * 500 + k];
        }
        const int k = ks + 496;
        if (k < 500) {
            const float uv = u[k];
#pragma unroll
            for (int o = 0; o < 10; ++o) acc[o] += uv * W[o * 500 + k];
        }
    }
#pragma unroll
    for (int o = 0; o < 10; ++o) red[(il * 10 + o) * 17 + ks] = acc[o];
    __syncthreads();
    if (t < 160) {
        const int il2 = t / 10, o = t - il2 * 10;
        float s = 0.f;
#pragma unroll
        for (int q = 0; q < 16; ++q) s += red[(il2 * 10 + o) * 17 + q];
        out[(size_t)(blk * 16 + il2) * 10 + o] = s + bias[o];
    }
}

// ============================ fused kernels ================================

__global__ __launch_bounds__(256) void k_prep(
    const float* x, const float* c1w, const float* c1b, float* h1,
    const float* l1c1w, bf16_t* Wb1, const float* l1c2w, bf16_t* Wb2,
    const float* c2w, float* w2p)
{
    extern __shared__ char smem[];
    const int g = blockIdx.x;
    if (g < 2704)        role_conv1(smem, g, x, c1w, c1b, h1);
    else if (g < 19664)  role_wb16(g - 2704, l1c1w, Wb1, 500, 8450, 8480, 512 * 8480);
    else if (g < 22224)  role_wb16(g - 19664, l1c2w, Wb2, 500, 1250, 1280, 512 * 1280);
    else                 role_w2t(g - 22224, c2w, w2p);
}

__global__ __launch_bounds__(256, 4) void k_stage1(
    const float* h1, const bf16_t* Wb1, const float* l1c1b, float* u, float* up,
    const float* d1w, const float* d1b, int* e1,
    const float* w2p, const float* c2b, float* h2)
{
    extern __shared__ char smem[];
    const int g = blockIdx.x;
    if (g < 512)         role_gemm(smem, g, h1, 8480, Wb1, l1c1b, u, up, 8480, 4256, 500, 512);
    else if (g < 2560)   role_conv2(smem, g - 512, h1, w2p, c2b, h2);
    else                 role_exit(smem, g - 2560, h1, 8480, 8450, d1w, d1b, e1);
}

__global__ __launch_bounds__(256) void k_stage2(
    const float* h2, const bf16_t* Wb2, const float* l1c2b, float* v, float* vp,
    const float* d2w, const float* d2b, int* e2,
    const float* c3w, const float* c3b, float* f3,
    const float* u, const float* up, const float* l2c1w, const float* l2c1b, float* out1)
{
    extern __shared__ char smem[];
    const int g = blockIdx.x;
    if (g < 512)         role_gemm(smem, g, h2, 1280, Wb2, l1c2b, v, vp, 1280, 640, 500, 512);
    else if (g < 1536)   role_conv3(smem, g - 512, h2, c3w, c3b, f3);
    else if (g < 1792)   role_lin10(smem, g - 1536, u, up, 512, l2c1w, l2c1b, out1);
    else                 role_exit(smem, g - 1792, h2, 1280, 1250, d2w, d2b, e2);
}

// k_tail: per block = 16 samples. lin10-2 (v/vp) -> o2loc; lin500 -> u3 LDS;
// lin10-3 (u3 LDS) -> o3loc; select + log_softmax -> out. FP per-(b,o)
// expressions identical to round 10's separate kernels.
__global__ __launch_bounds__(256) void k_tail(
    const float* __restrict__ v, const float* __restrict__ vp,
    const float* __restrict__ l2c2w, const float* __restrict__ l2c2b,
    const float* __restrict__ f3, const float* __restrict__ l1w, const float* __restrict__ l1b,
    const float* __restrict__ l2w, const float* __restrict__ l2b,
    const float* __restrict__ out1, const int* __restrict__ e1, const int* __restrict__ e2,
    float* __restrict__ out)
{
    __shared__ float fs[800];        // 16 x 50
    __shared__ float u3loc[8000];    // 16 x 500
    __shared__ float red[2720];      // 16 x 10 x 17
    __shared__ float o2loc[160];
    __shared__ float o3loc[160];

    const int t   = threadIdx.x;
    const int blk = blockIdx.x;
    const int ks  = t & 15;
    const int il  = t >> 4;

    // stage f3 for 16 images
    for (int i = t; i < 800; i += 256) fs[i] = f3[(size_t)blk * 800 + i];
    __syncthreads();

    // lin500 -> u3loc (same per-(b,o) expression as round 10's role_lin500)
    for (int im = 0; im < 16; ++im) {
        for (int o = t; o < 500; o += 256) {
            float s = 0.f;
#pragma unroll
            for (int k = 0; k < 50; ++k) s += fs[im * 50 + k] * l1w[o * 50 + k];
            u3loc[im * 500 + o] = fmaxf(s + l1b[o], 0.f);
        }
    }

    // lin10-2 from v/vp (global, ldu=512)
    {
        const float* uu  = v  + (size_t)(blk * 16 + il) * 512;
        const float* uu2 = vp + (size_t)(blk * 16 + il) * 512;
        float acc[10];
#pragma unroll
        for (int o = 0; o < 10; ++o) acc[o] = 0.f;
        for (int i = 0; i < 31; ++i) {
            const int k = ks + i * 16;
            const float uv = uu[k] + uu2[k];
#pragma unroll
            for (int o = 0; o < 10; ++o) acc[o] += uv * l2c2w[o * 500 + k];
        }
        const int k = ks + 496;
        if (k < 500) {
            const float uv = uu[k] + uu2[k];
#pragma unroll
            for (int o = 0; o < 10; ++o) acc[o] += uv * l2c2w[o * 500 + k];
        }
        __syncthreads();   // u3loc writes done; red free to use
#pragma unroll
        for (int o = 0; o < 10; ++o) red[(il * 10 + o) * 17 + ks] = acc[o];
        __syncthreads();
        if (t < 160) {
            const int il2 = t / 10, o = t - il2 * 10;
            float s = 0.f;
#pragma unroll
            for (int q = 0; q < 16; ++q) s += red[(il2 * 10 + o) * 17 + q];
            o2loc[t] = s + l2c2b[o];
        }
        __syncthreads();
    }

    // lin10-3 from u3loc (LDS, ldu=500)
    {
        const float* uu = u3loc + il * 500;
        float acc[10];
#pragma unroll
        for (int o = 0; o < 10; ++o) acc[o] = 0.f;
        for (int i = 0; i < 31; ++i) {
            const int k = ks + i * 16;
            const float uv = uu[k];
#pragma unroll
            for (int o = 0; o < 10; ++o) acc[o] += uv * l2w[o * 500 + k];
        }
        const int k = ks + 496;
        if (k < 500) {
            const float uv = uu[k];
#pragma unroll
            for (int o = 0; o < 10; ++o) acc[o] += uv * l2w[o * 500 + k];
        }
#pragma unroll
        for (int o = 0; o < 10; ++o) red[(il * 10 + o) * 17 + ks] = acc[o];
        __syncthreads();
        if (t < 160) {
            const int il2 = t / 10, o = t - il2 * 10;
            float s = 0.f;
#pragma unroll
            for (int q = 0; q < 16; ++q) s += red[(il2 * 10 + o) * 17 + q];
            o3loc[t] = s + l2b[o];
        }
        __syncthreads();
    }

    // select + log_softmax (one thread per sample)
    if (t < 16) {
        const int b = blk * 16 + t;
        float vv[10];
        if (e1[b]) {
            const float* src = out1 + (size_t)b * 10;
#pragma unroll
            for (int o = 0; o < 10; ++o) vv[o] = src[o];
        } else if (e2[b]) {
#pragma unroll
            for (int o = 0; o < 10; ++o) vv[o] = o2loc[t * 10 + o];
        } else {
#pragma unroll
            for (int o = 0; o < 10; ++o) vv[o] = o3loc[t * 10 + o];
        }
        float m = -3.4e38f;
#pragma unroll
        for (int o = 0; o < 10; ++o) m = fmaxf(m, vv[o]);
        float s = 0.f;
#pragma unroll
        for (int o = 0; o < 10; ++o) s += expf(vv[o] - m);
        const float ls = logf(s);
#pragma unroll
        for (int o = 0; o < 10; ++o) out[(size_t)b * 10 + o] = vv[o] - m - ls;
    }
}

// ---------------------------------------------------------------------------
static inline size_t align256(size_t v) { return (v + 255) & ~(size_t)255; }

extern "C" void kernel_launch(void* const* d_in, const int* in_sizes, int n_in,
                              void* d_out, int out_size, void* d_ws, size_t ws_size,
                              hipStream_t stream)
{
    const float* x     = (const float*)d_in[0];
    const float* c1w   = (const float*)d_in[1];
    const float* c1b   = (const float*)d_in[2];
    const float* c2w   = (const float*)d_in[3];
    const float* c2b   = (const float*)d_in[4];
    const float* c3w   = (const float*)d_in[5];
    const float* c3b   = (const float*)d_in[6];
    const float* l1c1w = (const float*)d_in[7];
    const float* l1c1b = (const float*)d_in[8];
    const float* l2c1w = (const float*)d_in[9];
    const float* l2c1b = (const float*)d_in[10];
    const float* l1c2w = (const float*)d_in[11];
    const float* l1c2b = (const float*)d_in[12];
    const float* l2c2w = (const float*)d_in[13];
    const float* l2c2b = (const float*)d_in[14];
    const float* l1w   = (const float*)d_in[15];
    const float* l1b   = (const float*)d_in[16];
    const float* l2w   = (const float*)d_in[17];
    const float* l2b   = (const float*)d_in[18];
    const float* d1w   = (const float*)d_in[19];
    const float* d1b   = (const float*)d_in[20];
    const float* d2w   = (const float*)d_in[21];
    const float* d2b   = (const float*)d_in[22];

    // ---- workspace layout (single chunk, B=4096; fits r9/r10-proven budget)
    size_t off = 0;
    const size_t oWb1  = off; off = align256(off + (size_t)512 * 8480 * 2);
    const size_t oWb2  = off; off = align256(off + (size_t)512 * 1280 * 2);
    const size_t oW2P  = off; off = align256(off + (size_t)50 * 600 * 4);
    const size_t oOut1 = off; off = align256(off + (size_t)B_IMG * 10 * 4);
    const size_t oE1   = off; off = align256(off + (size_t)B_IMG * 4);
    const size_t oE2   = off; off = align256(off + (size_t)B_IMG * 4);
    const size_t oH1   = off; off = align256(off + (size_t)B_IMG * 8480 * 4);
    const size_t oH2   = off; off = align256(off + (size_t)B_IMG * 1280 * 4);
    const size_t oU    = off; off = align256(off + (size_t)B_IMG * 512 * 4);
    const size_t oUP   = off; off = align256(off + (size_t)B_IMG * 512 * 4);
    const size_t oF3   = off; off = align256(off + (size_t)B_IMG * 50 * 4);

    char* ws = (char*)d_ws;
    bf16_t* Wb1  = (bf16_t*)(ws + oWb1);
    bf16_t* Wb2  = (bf16_t*)(ws + oWb2);
    float*  w2p  = (float*) (ws + oW2P);
    float*  out1 = (float*) (ws + oOut1);
    int*    e1   = (int*)   (ws + oE1);
    int*    e2   = (int*)   (ws + oE2);
    float*  h1   = (float*) (ws + oH1);
    float*  h2   = (float*) (ws + oH2);
    float*  u    = (float*) (ws + oU);
    float*  up   = (float*) (ws + oUP);
    float*  f3   = (float*) (ws + oF3);
    // stage-2 gemm outputs carved from the dead h1 region
    float*  v    = h1;                          // 4096*512 f32
    float*  vp   = h1 + (size_t)B_IMG * 512;    // 4096*512 f32

    float* out = (float*)d_out;

    // P: conv1 + weight conversions (all independent)
    k_prep<<<22342, 256, 2048, stream>>>(x, c1w, c1b, h1, l1c1w, Wb1, l1c2w, Wb2, c2w, w2p);
    // A: gemm1 | conv2 | exit1  (consume h1); 15488 B LDS (gemm floor 15360)
    k_stage1<<<6656, 256, 15488, stream>>>(h1, Wb1, l1c1b, u, up, d1w, d1b, e1, w2p, c2b, h2);
    // C: gemm2 | conv3 | lin10-1 | exit2  (consume h2 / stage1-u)
    k_stage2<<<5888, 256, 20000, stream>>>(h2, Wb2, l1c2b, v, vp, d2w, d2b, e2,
                                           c3w, c3b, f3, u, up, l2c1w, l2c1b, out1);
    // T: lin10-2 | lin500 | lin10-3 | select  (per-16-sample blocks)
    k_tail<<<256, 256, 0, stream>>>(v, vp, l2c2w, l2c2b, f3, l1w, l1b, l2w, l2b,
                                    out1, e1, e2, out);

    (void)in_sizes; (void)n_in; (void)out_size; (void)ws_size;
}

// Round 2
// 817.038 us; speedup vs baseline: 1.2025x; 1.2025x over previous
//
#include <hip/hip_runtime.h>
#include <hip/hip_bf16.h>
#include <cstdint>

// ---------------------------------------------------------------------------
// ThreeLayerCNN (BranchyNet early-exit), B=4096.
// Precision: conv1/conv2/exit1/exit2 fp32 (argmax parity with numpy ref);
// big FC GEMMs (l1c1, l1c2) bf16 MFMA w/ fp32 accum (output tol 0.146).
// Round 13 (post-mortem of r12 spill disaster: VGPR cap 64 + acc[10][4] ->
// 322MB scratch writes; reverted to r11 register shape):
//  - conv2: r11-proven shape (1 img/block, 250 thr = 10 ocg x 25 pos,
//    acc[5][4], LDS-staged weights, verbatim fp32 tap tree, ic order 0..49)
//    with 5-ic chunks (10 chunks, no tail; 12 barriers vs 13) and T14
//    issue-early/write-late staging (istg[4]+wstg[3] regs, ~105 VGPR).
//  - exit1 FOLDED into conv2: per-chunk d1w partial dots on the staged
//    chunk (845*10 == K=8450 exactly), wave-shuffle + tiny LDS reduce.
//    Removes 4096 exit blocks + 139 MB h1 re-reads. stage1 grid 8704->4608.
//  - exit2 FOLDED into conv3 (1 wave == 1 image -> pure shuffle reduce).
//    stage2 grid 5888->1792.
//  - NO min-waves launch bounds anywhere (r12 lesson).
// ---------------------------------------------------------------------------

typedef __bf16 bf16_t;
typedef __bf16 bf16x8 __attribute__((ext_vector_type(8)));
typedef float  f32x4  __attribute__((ext_vector_type(4)));

#define B_IMG 4096

// ======================= role bodies (device functions) =====================

__device__ void role_conv1(char* smem, int blk,
    const float* __restrict__ x, const float* __restrict__ w1,
    const float* __restrict__ b1, float* __restrict__ h1)
{
    float* ws = (float*)smem;        // 450
    float* bs = ws + 456;            // 50
    const int t = threadIdx.x;
    for (int i = t; i < 450; i += 256) ws[i] = w1[i];
    if (t < 50) bs[t] = b1[t];
    __syncthreads();

    const int idx = blk * 256 + t;
    if (idx >= B_IMG * 169) return;
    const int b   = idx / 169;
    const int pos = idx % 169;
    const int py = pos / 13, px = pos % 13;

    const float* xp = x + (size_t)b * 784 + (2 * py) * 28 + 2 * px;
    float p[4][4];
#pragma unroll
    for (int r = 0; r < 4; ++r)
#pragma unroll
        for (int c = 0; c < 4; ++c) p[r][c] = xp[r * 28 + c];

    float* hb = h1 + (size_t)b * 8480 + pos;
    if (pos < 30) h1[(size_t)b * 8480 + 8450 + pos] = 0.f;   // zero pad cols

    for (int oc = 0; oc < 50; ++oc) {
        const float* wp = &ws[oc * 9];
        const float w00 = wp[0], w01 = wp[1], w02 = wp[2];
        const float w10 = wp[3], w11 = wp[4], w12 = wp[5];
        const float w20 = wp[6], w21 = wp[7], w22 = wp[8];
        float a[2][2];
#pragma unroll
        for (int dy = 0; dy < 2; ++dy)
#pragma unroll
            for (int dx = 0; dx < 2; ++dx) {
                a[dy][dx] = p[dy + 0][dx + 0] * w00 + p[dy + 0][dx + 1] * w01 + p[dy + 0][dx + 2] * w02
                          + p[dy + 1][dx + 0] * w10 + p[dy + 1][dx + 1] * w11 + p[dy + 1][dx + 2] * w12
                          + p[dy + 2][dx + 0] * w20 + p[dy + 2][dx + 1] * w21 + p[dy + 2][dx + 2] * w22;
            }
        float v = fmaxf(fmaxf(a[0][0], a[0][1]), fmaxf(a[1][0], a[1][1])) + bs[oc];
        hb[oc * 169] = fmaxf(v, 0.f);
    }
}

__device__ void role_wb16(int blk, const float* __restrict__ src,
                          bf16_t* __restrict__ dst, int N, int K, int Kp, int total)
{
    const int idx = blk * 256 + threadIdx.x;
    if (idx >= total) return;
    const int n = idx / Kp, k = idx % Kp;
    const float v = (n < N && k < K) ? src[(size_t)n * K + k] : 0.f;
    dst[idx] = (bf16_t)v;
}

__device__ void role_w2t(int blk, const float* __restrict__ w2, float* __restrict__ w2p)
{
    const int idx = blk * 256 + threadIdx.x;
    if (idx >= 50 * 600) return;
    const int ic = idx / 600, r = idx % 600, oc = r / 12, j = r % 12;
    w2p[idx] = (j < 9) ? w2[oc * 450 + ic * 9 + j] : 0.f;
}

// conv2 (50->50) + relu + pool + FOLDED exit1.
// r11-proven thread shape: 1 img/block, t<250 active (ocg=t/25 in 0..9,
// 5 oc each), acc[5][4]. Input+weights double-buffered in LDS, 5-ic chunks
// (10 chunks, ic order 0..49 sequential, verbatim 9-term tap expression ->
// h2 bit-identical to r8..r11 -> exit2 argmax parity).
// exit1: each chunk is 845 h1 floats (10*845 == 8450 == K); all 256 threads
// accumulate d1w partial dots from the staged chunk, shuffle+LDS reduce.
__device__ void role_conv2(char* smem, int b,
    const float* __restrict__ h1, const float* __restrict__ w2p,
    const float* __restrict__ b2, float* __restrict__ h2,
    const float* __restrict__ d1w, const float* __restrict__ d1b,
    int* __restrict__ e1)
{
    float* in   = (float*)smem;          // [2][845] (region padded to 1696)
    float* wbuf = in + 1696;             // [2][3000], 16B-aligned (1696*4)
    const int t = threadIdx.x;
    const float* hb = h1 + (size_t)b * 8480;

    // stage chunk 0 (ic 0..4): input + weights
    for (int s = t; s < 845; s += 256) in[s] = hb[s];
    {
        const float4* src = (const float4*)w2p;
        float4* dst = (float4*)wbuf;
        for (int s = t; s < 750; s += 256) dst[s] = src[s];
    }
    __syncthreads();
    if (t < 30) h2[(size_t)b * 1280 + 1250 + t] = 0.f;       // zero pad cols

    const int ocg = t / 25;              // 0..9
    const int pos = t % 25;
    const int py = pos / 5, px = pos % 5;
    const int oc0 = ocg * 5;
    const bool act = (t < 250);

    float acc[5][4];
#pragma unroll
    for (int j = 0; j < 5; ++j)
#pragma unroll
        for (int q = 0; q < 4; ++q) acc[j][q] = 0.f;

    float ex0 = 0.f, ex1 = 0.f;          // folded exit1 partials

    const float* ib0 = in + (2 * py) * 13 + 2 * px;

    for (int c = 0; c < 10; ++c) {       // 10 chunks x 5 ic = ic 0..49 in order
        const int cur = c & 1;

        // T14: issue next-chunk global loads early, write to LDS late
        float istg[4];
        float4 wstg[3];
        if (c < 9) {
            const float* isrc = hb + (c + 1) * 845;
#pragma unroll
            for (int u = 0; u < 4; ++u) {
                const int s = t + u * 256;
                if (s < 845) istg[u] = isrc[s];
            }
            const float4* wsrc = (const float4*)(w2p + (size_t)(c + 1) * 3000);
#pragma unroll
            for (int u = 0; u < 3; ++u) {
                const int s = t + u * 256;
                if (s < 750) wstg[u] = wsrc[s];
            }
        }

        if (act) {
            const float* ibc = ib0 + cur * 845;
            const float* wcb = wbuf + cur * 3000 + oc0 * 12;
#pragma unroll 1
            for (int icl = 0; icl < 5; ++icl) {
                float p[4][4];
                const float* ip = ibc + icl * 169;
#pragma unroll
                for (int r = 0; r < 4; ++r)
#pragma unroll
                    for (int cc = 0; cc < 4; ++cc) p[r][cc] = ip[r * 13 + cc];
                const float* wl = wcb + icl * 600;
#pragma unroll
                for (int j = 0; j < 5; ++j) {
                    const f32x4 wv0 = *(const f32x4*)(wl + j * 12);
                    const f32x4 wv1 = *(const f32x4*)(wl + j * 12 + 4);
                    const f32x4 wv2 = *(const f32x4*)(wl + j * 12 + 8);
                    const float w00 = wv0[0], w01 = wv0[1], w02 = wv0[2];
                    const float w10 = wv0[3], w11 = wv1[0], w12 = wv1[1];
                    const float w20 = wv1[2], w21 = wv1[3], w22 = wv2[0];
#pragma unroll
                    for (int dy = 0; dy < 2; ++dy)
#pragma unroll
                        for (int dx = 0; dx < 2; ++dx) {
                            acc[j][dy * 2 + dx] +=
                                  p[dy + 0][dx + 0] * w00 + p[dy + 0][dx + 1] * w01 + p[dy + 0][dx + 2] * w02
                                + p[dy + 1][dx + 0] * w10 + p[dy + 1][dx + 1] * w11 + p[dy + 1][dx + 2] * w12
                                + p[dy + 2][dx + 0] * w20 + p[dy + 2][dx + 1] * w21 + p[dy + 2][dx + 2] * w22;
                        }
                }
            }
        }

        // folded exit1: partial dots over this staged chunk (all 256 threads)
        {
            const float* dwa = d1w + c * 845;
            const float* dwb = d1w + 8450 + c * 845;
            const float* inc = in + cur * 845;
#pragma unroll
            for (int u = 0; u < 4; ++u) {
                const int s = t + u * 256;
                if (s < 845) {
                    const float vv = inc[s];
                    ex0 += vv * dwa[s];
                    ex1 += vv * dwb[s];
                }
            }
        }

        if (c < 9) {                     // write-late into the other buffer
            const int nxt = cur ^ 1;
#pragma unroll
            for (int u = 0; u < 4; ++u) {
                const int s = t + u * 256;
                if (s < 845) in[nxt * 845 + s] = istg[u];
            }
            float4* wdst = (float4*)(wbuf + nxt * 3000);
#pragma unroll
            for (int u = 0; u < 3; ++u) {
                const int s = t + u * 256;
                if (s < 750) wdst[s] = wstg[u];
            }
        }
        __syncthreads();
    }

    if (act) {
#pragma unroll
        for (int j = 0; j < 5; ++j) {
            float v = fmaxf(fmaxf(acc[j][0], acc[j][1]), fmaxf(acc[j][2], acc[j][3]));
            h2[(size_t)b * 1280 + (oc0 + j) * 25 + pos] = fmaxf(v + b2[oc0 + j], 0.f);
        }
    }

    // exit1 reduce: wave shuffle, then 4 wave-partials via LDS (in[] is dead)
#pragma unroll
    for (int off = 32; off > 0; off >>= 1) {
        ex0 += __shfl_down(ex0, off);
        ex1 += __shfl_down(ex1, off);
    }
    float* r = (float*)smem;
    const int wv = t >> 6;
    if ((t & 63) == 0) { r[wv] = ex0; r[8 + wv] = ex1; }
    __syncthreads();
    if (t == 0) {
        const float s0 = r[0] + r[1] + r[2] + r[3] + d1b[0];
        const float s1 = r[8] + r[9] + r[10] + r[11] + d1b[1];
        e1[b] = (s0 >= s1) ? 1 : 0;
    }
}

// conv3 + relu + pool + FOLDED exit2. 4 img/block; wave il == image il,
// so exit2 is a pure shuffle reduce (no barrier, no LDS).
__device__ void role_conv3x(char* smem, int blk,
    const float* __restrict__ h2, const float* __restrict__ w3,
    const float* __restrict__ b3,
    const float* __restrict__ d2w, const float* __restrict__ d2b,
    int* __restrict__ e2, float* __restrict__ f3)
{
    float* in = (float*)smem;    // 5000
    const int t = threadIdx.x;
    for (int i = t; i < 5000; i += 256) {
        const int img = i / 1250, off = i % 1250;
        in[i] = h2[(size_t)(blk * 4 + img) * 1280 + off];
    }
    __syncthreads();
    const int il   = t >> 6;
    const int lane = t & 63;

    // folded exit2: one wave per image, strided dot + shuffle tree
    {
        const float* ip = &in[il * 1250];
        float s0 = 0.f, s1 = 0.f;
        for (int i = lane; i < 1250; i += 64) {
            const float vv = ip[i];
            s0 += vv * d2w[i];
            s1 += vv * d2w[1250 + i];
        }
#pragma unroll
        for (int off = 32; off > 0; off >>= 1) {
            s0 += __shfl_down(s0, off);
            s1 += __shfl_down(s1, off);
        }
        if (lane == 0) e2[blk * 4 + il] = (s0 + d2b[0] >= s1 + d2b[1]) ? 1 : 0;
    }

    const int oc = lane;
    if (oc >= 50) return;

    const float* ip0 = &in[il * 1250];
    float a00 = 0.f, a01 = 0.f, a10 = 0.f, a11 = 0.f;
    for (int ic = 0; ic < 50; ++ic) {
        float p[4][4];
        const float* ip = ip0 + ic * 25;
#pragma unroll
        for (int r = 0; r < 4; ++r)
#pragma unroll
            for (int c = 0; c < 4; ++c) p[r][c] = ip[r * 5 + c];
        const float* wp = &w3[((size_t)oc * 50 + ic) * 9];
        const float w00 = wp[0], w01 = wp[1], w02 = wp[2];
        const float w10 = wp[3], w11 = wp[4], w12 = wp[5];
        const float w20 = wp[6], w21 = wp[7], w22 = wp[8];
        a00 += p[0][0]*w00 + p[0][1]*w01 + p[0][2]*w02 + p[1][0]*w10 + p[1][1]*w11 + p[1][2]*w12 + p[2][0]*w20 + p[2][1]*w21 + p[2][2]*w22;
        a01 += p[0][1]*w00 + p[0][2]*w01 + p[0][3]*w02 + p[1][1]*w10 + p[1][2]*w11 + p[1][3]*w12 + p[2][1]*w20 + p[2][2]*w21 + p[2][3]*w22;
        a10 += p[1][0]*w00 + p[1][1]*w01 + p[1][2]*w02 + p[2][0]*w10 + p[2][1]*w11 + p[2][2]*w12 + p[3][0]*w20 + p[3][1]*w21 + p[3][2]*w22;
        a11 += p[1][1]*w00 + p[1][2]*w01 + p[1][3]*w02 + p[2][1]*w10 + p[2][2]*w11 + p[2][3]*w12 + p[3][1]*w20 + p[3][2]*w21 + p[3][3]*w22;
    }
    float v = fmaxf(fmaxf(a00, a01), fmaxf(a10, a11)) + b3[oc];
    f3[(size_t)(blk * 4 + il) * 50 + oc] = fmaxf(v, 0.f);
}

// MFMA GEMM split-K=2 (r9-proven). g in [0,512): bx=g&31, by=(g>>5)&7, kz=g>>8.
__device__ void role_gemm(char* smem, int g,
    const float* __restrict__ A, int lda, const bf16_t* __restrict__ W,
    const float* __restrict__ bias, float* __restrict__ C0, float* __restrict__ C1,
    int Kp, int khalf, int Nout, int ldc)
{
    bf16_t* As = (bf16_t*)smem;      // 128*40
    bf16_t* Bs = As + 128 * 40;      // 64*40

    const int t = threadIdx.x;
    const int m0 = (g & 31) * 128;
    const int n0 = ((g >> 5) & 7) * 64;
    const int kz = g >> 8;
    const int kbeg = kz ? khalf : 0;
    const int kend = kz ? Kp : khalf;
    float* C = kz ? C1 : C0;

    const int wave = t >> 6;
    const int lane = t & 63;
    const int wm = (wave >> 1) * 64;
    const int wn = (wave & 1) * 32;
    const int quad = lane >> 4;
    const int lr = lane & 15;

    f32x4 acc[4][2];
#pragma unroll
    for (int i = 0; i < 4; ++i)
#pragma unroll
        for (int j = 0; j < 2; ++j) acc[i][j] = (f32x4)0.f;

    const int ar = t >> 2;
    const int ac = (t & 3) * 8;

    for (int k0 = kbeg; k0 < kend; k0 += 32) {
        __syncthreads();
#pragma unroll
        for (int h = 0; h < 2; ++h) {
            const float* ap = A + (size_t)(m0 + ar + h * 64) * lda + k0 + ac;
            const float4 f0 = *(const float4*)ap;
            const float4 f1 = *(const float4*)(ap + 4);
            bf16x8 v;
            v[0] = (bf16_t)f0.x; v[1] = (bf16_t)f0.y; v[2] = (bf16_t)f0.z; v[3] = (bf16_t)f0.w;
            v[4] = (bf16_t)f1.x; v[5] = (bf16_t)f1.y; v[6] = (bf16_t)f1.z; v[7] = (bf16_t)f1.w;
            *(bf16x8*)&As[(ar + h * 64) * 40 + ac] = v;
        }
        *(uint4*)&Bs[ar * 40 + ac] = *(const uint4*)&W[(size_t)(n0 + ar) * Kp + k0 + ac];
        __syncthreads();

        bf16x8 af[4], bfr[2];
#pragma unroll
        for (int i = 0; i < 4; ++i)
            af[i] = *(const bf16x8*)&As[(wm + i * 16 + lr) * 40 + quad * 8];
#pragma unroll
        for (int j = 0; j < 2; ++j)
            bfr[j] = *(const bf16x8*)&Bs[(wn + j * 16 + lr) * 40 + quad * 8];
#pragma unroll
        for (int i = 0; i < 4; ++i)
#pragma unroll
            for (int j = 0; j < 2; ++j)
                acc[i][j] = __builtin_amdgcn_mfma_f32_16x16x32_bf16(af[i], bfr[j], acc[i][j], 0, 0, 0);
    }

#pragma unroll
    for (int j = 0; j < 2; ++j) {
        const int n = n0 + wn + j * 16 + lr;
        const float bv = (kz == 0 && n < Nout) ? bias[n] : 0.f;
#pragma unroll
        for (int i = 0; i < 4; ++i) {
            const int mrow = m0 + wm + i * 16 + quad * 4;
#pragma unroll
            for (int r = 0; r < 4; ++r)
                C[(size_t)(mrow + r) * ldc + n] = acc[i][j][r] + bv;
        }
    }
}

// lin10: out[b,o<10] = (U[+U2]) @ W^T + bias; 16 img x 16 k-strips per block.
__device__ void role_lin10(char* smem, int blk,
    const float* __restrict__ U, const float* __restrict__ U2, int ldu,
    const float* __restrict__ W, const float* __restrict__ bias,
    float* __restrict__ out)
{
    float* red = (float*)smem;   // [16][10][17]
    const int t = threadIdx.x;
    const int ks = t & 15;
    const int il = t >> 4;
    const int b  = blk * 16 + il;
    const float* u = U + (size_t)b * ldu;

    float acc[10];
#pragma unroll
    for (int o = 0; o < 10; ++o) acc[o] = 0.f;

    if (U2) {
        const float* u2 = U2 + (size_t)b * ldu;
        for (int i = 0; i < 31; ++i) {
            const int k = ks + i * 16;
            const float uv = u[k] + u2[k];
#pragma unroll
            for (int o = 0; o < 10; ++o) acc[o] += uv * W[o * 500 + k];
        }
        const int k = ks + 496;
        if (k < 500) {
            const float uv = u[k] + u2[k];
#pragma unroll
            for (int o = 0; o < 10; ++o) acc[o] += uv * W[o * 500 + k];
        }
    } else {
        for (int i = 0; i < 31; ++i) {
            const int k = ks + i * 16;
            const float uv = u[k];
#pragma unroll
            for (int o = 0; o < 10; ++o) acc[o] += uv * W[o * 500 + k];
        }
        const int k = ks + 496;
        if (k < 500) {
            const float uv = u[k];
#pragma unroll
            for (int o = 0; o < 10; ++o) acc[o] += uv * W[o * 500 + k];
        }
    }
#pragma unroll
    for (int o = 0; o < 10; ++o) red[(il * 10 + o) * 17 + ks] = acc[o];
    __syncthreads();
    if (t < 160) {
        const int il2 = t / 10, o = t - il2 * 10;
        float s = 0.f;
#pragma unroll
        for (int q = 0; q < 16; ++q) s += red[(il2 * 10 + o) * 17 + q];
        out[(size_t)(blk * 16 + il2) * 10 + o] = s + bias[o];
    }
}

// ============================ fused kernels ================================

__global__ __launch_bounds__(256) void k_prep(
    const float* x, const float* c1w, const float* c1b, float* h1,
    const float* l1c1w, bf16_t* Wb1, const float* l1c2w, bf16_t* Wb2,
    const float* c2w, float* w2p)
{
    extern __shared__ char smem[];
    const int g = blockIdx.x;
    if (g < 2704)        role_conv1(smem, g, x, c1w, c1b, h1);
    else if (g < 19664)  role_wb16(g - 2704, l1c1w, Wb1, 500, 8450, 8480, 512 * 8480);
    else if (g < 22224)  role_wb16(g - 19664, l1c2w, Wb2, 500, 1250, 1280, 512 * 1280);
    else                 role_w2t(g - 22224, c2w, w2p);
}

__global__ __launch_bounds__(256) void k_stage1(
    const float* h1, const bf16_t* Wb1, const float* l1c1b, float* u, float* up,
    const float* d1w, const float* d1b, int* e1,
    const float* w2p, const float* c2b, float* h2)
{
    extern __shared__ char smem[];
    const int g = blockIdx.x;
    if (g < 512)         role_gemm(smem, g, h1, 8480, Wb1, l1c1b, u, up, 8480, 4256, 500, 512);
    else                 role_conv2(smem, g - 512, h1, w2p, c2b, h2, d1w, d1b, e1);
}

__global__ __launch_bounds__(256) void k_stage2(
    const float* h2, const bf16_t* Wb2, const float* l1c2b, float* v, float* vp,
    const float* d2w, const float* d2b, int* e2,
    const float* c3w, const float* c3b, float* f3,
    const float* u, const float* up, const float* l2c1w, const float* l2c1b, float* out1)
{
    extern __shared__ char smem[];
    const int g = blockIdx.x;
    if (g < 512)         role_gemm(smem, g, h2, 1280, Wb2, l1c2b, v, vp, 1280, 640, 500, 512);
    else if (g < 1536)   role_conv3x(smem, g - 512, h2, c3w, c3b, d2w, d2b, e2, f3);
    else                 role_lin10(smem, g - 1536, u, up, 512, l2c1w, l2c1b, out1);
}

// k_tail: per block = 16 samples. lin10-2 (v/vp) -> o2loc; lin500 -> u3 LDS;
// lin10-3 (u3 LDS) -> o3loc; select + log_softmax -> out. FP per-(b,o)
// expressions identical to round 10's separate kernels.
__global__ __launch_bounds__(256) void k_tail(
    const float* __restrict__ v, const float* __restrict__ vp,
    const float* __restrict__ l2c2w, const float* __restrict__ l2c2b,
    const float* __restrict__ f3, const float* __restrict__ l1w, const float* __restrict__ l1b,
    const float* __restrict__ l2w, const float* __restrict__ l2b,
    const float* __restrict__ out1, const int* __restrict__ e1, const int* __restrict__ e2,
    float* __restrict__ out)
{
    __shared__ float fs[800];        // 16 x 50
    __shared__ float u3loc[8000];    // 16 x 500
    __shared__ float red[2720];      // 16 x 10 x 17
    __shared__ float o2loc[160];
    __shared__ float o3loc[160];

    const int t   = threadIdx.x;
    const int blk = blockIdx.x;
    const int ks  = t & 15;
    const int il  = t >> 4;

    // stage f3 for 16 images
    for (int i = t; i < 800; i += 256) fs[i] = f3[(size_t)blk * 800 + i];
    __syncthreads();

    // lin500 -> u3loc (same per-(b,o) expression as round 10's role_lin500)
    for (int im = 0; im < 16; ++im) {
        for (int o = t; o < 500; o += 256) {
            float s = 0.f;
#pragma unroll
            for (int k = 0; k < 50; ++k) s += fs[im * 50 + k] * l1w[o * 50 + k];
            u3loc[im * 500 + o] = fmaxf(s + l1b[o], 0.f);
        }
    }

    // lin10-2 from v/vp (global, ldu=512)
    {
        const float* uu  = v  + (size_t)(blk * 16 + il) * 512;
        const float* uu2 = vp + (size_t)(blk * 16 + il) * 512;
        float acc[10];
#pragma unroll
        for (int o = 0; o < 10; ++o) acc[o] = 0.f;
        for (int i = 0; i < 31; ++i) {
            const int k = ks + i * 16;
            const float uv = uu[k] + uu2[k];
#pragma unroll
            for (int o = 0; o < 10; ++o) acc[o] += uv * l2c2w[o * 500 + k];
        }
        const int k = ks + 496;
        if (k < 500) {
            const float uv = uu[k] + uu2[k];
#pragma unroll
            for (int o = 0; o < 10; ++o) acc[o] += uv * l2c2w[o * 500 + k];
        }
        __syncthreads();   // u3loc writes done; red free to use
#pragma unroll
        for (int o = 0; o < 10; ++o) red[(il * 10 + o) * 17 + ks] = acc[o];
        __syncthreads();
        if (t < 160) {
            const int il2 = t / 10, o = t - il2 * 10;
            float s = 0.f;
#pragma unroll
            for (int q = 0; q < 16; ++q) s += red[(il2 * 10 + o) * 17 + q];
            o2loc[t] = s + l2c2b[o];
        }
        __syncthreads();
    }

    // lin10-3 from u3loc (LDS, ldu=500)
    {
        const float* uu = u3loc + il * 500;
        float acc[10];
#pragma unroll
        for (int o = 0; o < 10; ++o) acc[o] = 0.f;
        for (int i = 0; i < 31; ++i) {
            const int k = ks + i * 16;
            const float uv = uu[k];
#pragma unroll
            for (int o = 0; o < 10; ++o) acc[o] += uv * l2w[o * 500 + k];
        }
        const int k = ks + 496;
        if (k < 500) {
            const float uv = uu[k];
#pragma unroll
            for (int o = 0; o < 10; ++o) acc[o] += uv * l2w[o * 500 + k];
        }
#pragma unroll
        for (int o = 0; o < 10; ++o) red[(il * 10 + o) * 17 + ks] = acc[o];
        __syncthreads();
        if (t < 160) {
            const int il2 = t / 10, o = t - il2 * 10;
            float s = 0.f;
#pragma unroll
            for (int q = 0; q < 16; ++q) s += red[(il2 * 10 + o) * 17 + q];
            o3loc[t] = s + l2b[o];
        }
        __syncthreads();
    }

    // select + log_softmax (one thread per sample)
    if (t < 16) {
        const int b = blk * 16 + t;
        float vv[10];
        if (e1[b]) {
            const float* src = out1 + (size_t)b * 10;
#pragma unroll
            for (int o = 0; o < 10; ++o) vv[o] = src[o];
        } else if (e2[b]) {
#pragma unroll
            for (int o = 0; o < 10; ++o) vv[o] = o2loc[t * 10 + o];
        } else {
#pragma unroll
            for (int o = 0; o < 10; ++o) vv[o] = o3loc[t * 10 + o];
        }
        float m = -3.4e38f;
#pragma unroll
        for (int o = 0; o < 10; ++o) m = fmaxf(m, vv[o]);
        float s = 0.f;
#pragma unroll
        for (int o = 0; o < 10; ++o) s += expf(vv[o] - m);
        const float ls = logf(s);
#pragma unroll
        for (int o = 0; o < 10; ++o) out[(size_t)b * 10 + o] = vv[o] - m - ls;
    }
}

// ---------------------------------------------------------------------------
static inline size_t align256(size_t v) { return (v + 255) & ~(size_t)255; }

extern "C" void kernel_launch(void* const* d_in, const int* in_sizes, int n_in,
                              void* d_out, int out_size, void* d_ws, size_t ws_size,
                              hipStream_t stream)
{
    const float* x     = (const float*)d_in[0];
    const float* c1w   = (const float*)d_in[1];
    const float* c1b   = (const float*)d_in[2];
    const float* c2w   = (const float*)d_in[3];
    const float* c2b   = (const float*)d_in[4];
    const float* c3w   = (const float*)d_in[5];
    const float* c3b   = (const float*)d_in[6];
    const float* l1c1w = (const float*)d_in[7];
    const float* l1c1b = (const float*)d_in[8];
    const float* l2c1w = (const float*)d_in[9];
    const float* l2c1b = (const float*)d_in[10];
    const float* l1c2w = (const float*)d_in[11];
    const float* l1c2b = (const float*)d_in[12];
    const float* l2c2w = (const float*)d_in[13];
    const float* l2c2b = (const float*)d_in[14];
    const float* l1w   = (const float*)d_in[15];
    const float* l1b   = (const float*)d_in[16];
    const float* l2w   = (const float*)d_in[17];
    const float* l2b   = (const float*)d_in[18];
    const float* d1w   = (const float*)d_in[19];
    const float* d1b   = (const float*)d_in[20];
    const float* d2w   = (const float*)d_in[21];
    const float* d2b   = (const float*)d_in[22];

    // ---- workspace layout (single chunk, B=4096; fits r9/r10-proven budget)
    size_t off = 0;
    const size_t oWb1  = off; off = align256(off + (size_t)512 * 8480 * 2);
    const size_t oWb2  = off; off = align256(off + (size_t)512 * 1280 * 2);
    const size_t oW2P  = off; off = align256(off + (size_t)50 * 600 * 4);
    const size_t oOut1 = off; off = align256(off + (size_t)B_IMG * 10 * 4);
    const size_t oE1   = off; off = align256(off + (size_t)B_IMG * 4);
    const size_t oE2   = off; off = align256(off + (size_t)B_IMG * 4);
    const size_t oH1   = off; off = align256(off + (size_t)B_IMG * 8480 * 4);
    const size_t oH2   = off; off = align256(off + (size_t)B_IMG * 1280 * 4);
    const size_t oU    = off; off = align256(off + (size_t)B_IMG * 512 * 4);
    const size_t oUP   = off; off = align256(off + (size_t)B_IMG * 512 * 4);
    const size_t oF3   = off; off = align256(off + (size_t)B_IMG * 50 * 4);

    char* ws = (char*)d_ws;
    bf16_t* Wb1  = (bf16_t*)(ws + oWb1);
    bf16_t* Wb2  = (bf16_t*)(ws + oWb2);
    float*  w2p  = (float*) (ws + oW2P);
    float*  out1 = (float*) (ws + oOut1);
    int*    e1   = (int*)   (ws + oE1);
    int*    e2   = (int*)   (ws + oE2);
    float*  h1   = (float*) (ws + oH1);
    float*  h2   = (float*) (ws + oH2);
    float*  u    = (float*) (ws + oU);
    float*  up   = (float*) (ws + oUP);
    float*  f3   = (float*) (ws + oF3);
    // stage-2 gemm outputs carved from the dead h1 region
    float*  v    = h1;                          // 4096*512 f32
    float*  vp   = h1 + (size_t)B_IMG * 512;    // 4096*512 f32

    float* out = (float*)d_out;

    // P: conv1 + weight conversions (all independent)
    k_prep<<<22342, 256, 2048, stream>>>(x, c1w, c1b, h1, l1c1w, Wb1, l1c2w, Wb2, c2w, w2p);
    // A: gemm1 | conv2+exit1  (consume h1); LDS 30784 B (conv2: 1696+6000 f)
    k_stage1<<<4608, 256, 30784, stream>>>(h1, Wb1, l1c1b, u, up, d1w, d1b, e1, w2p, c2b, h2);
    // C: gemm2 | conv3+exit2 | lin10-1  (consume h2 / stage1-u)
    k_stage2<<<1792, 256, 20000, stream>>>(h2, Wb2, l1c2b, v, vp, d2w, d2b, e2,
                                           c3w, c3b, f3, u, up, l2c1w, l2c1b, out1);
    // T: lin10-2 | lin500 | lin10-3 | select  (per-16-sample blocks)
    k_tail<<<256, 256, 0, stream>>>(v, vp, l2c2w, l2c2b, f3, l1w, l1b, l2w, l2b,
                                    out1, e1, e2, out);

    (void)in_sizes; (void)n_in; (void)out_size; (void)ws_size;
}

// Round 3
// 752.230 us; speedup vs baseline: 1.3061x; 1.0862x over previous
//
#include <hip/hip_runtime.h>
#include <hip/hip_bf16.h>
#include <cstdint>

// ---------------------------------------------------------------------------
// ThreeLayerCNN (BranchyNet early-exit), B=4096.
// Precision: conv1/conv2/exit1/exit2 fp32 (argmax parity with numpy ref);
// big FC GEMMs (l1c1, l1c2) bf16 MFMA w/ fp32 accum (output tol 0.146).
// Round 14 (post-mortems: r12 = spill disaster from launch-bound VGPR cap;
// r13 = exit1 fold put L2-latency loads on conv2's barrier-serialized path
// AND removed the 4096 independent exit blocks that were filling stall
// slots -> occupancy 34->23%, stage1 469->543):
//  - k_stage1 back to r11-proven 3-role split: gemm 512 | conv2 4096 |
//    exit1 4096 (grid 8704, LDS 24832). Exit blocks = free latency filler.
//  - conv2: r11 structure (4-ic chunks, direct global->LDS staging, dbuf,
//    acc[5][4]) with ONE change: ic unrolled by 2 (pa/pb) so 32 p-loads
//    issue per compute burst instead of 16 -> halves exposed LDS latency.
//    Per-acc ic order still strict 0..49, verbatim tap tree -> h2
//    bit-identical -> exit2 argmax parity. ~+16 VGPR, no launch bounds.
//  - stage2 keeps r13's conv3x (folded exit2, neutral measured).
// ---------------------------------------------------------------------------

typedef __bf16 bf16_t;
typedef __bf16 bf16x8 __attribute__((ext_vector_type(8)));
typedef float  f32x4  __attribute__((ext_vector_type(4)));

#define B_IMG 4096

// ======================= role bodies (device functions) =====================

__device__ void role_conv1(char* smem, int blk,
    const float* __restrict__ x, const float* __restrict__ w1,
    const float* __restrict__ b1, float* __restrict__ h1)
{
    float* ws = (float*)smem;        // 450
    float* bs = ws + 456;            // 50
    const int t = threadIdx.x;
    for (int i = t; i < 450; i += 256) ws[i] = w1[i];
    if (t < 50) bs[t] = b1[t];
    __syncthreads();

    const int idx = blk * 256 + t;
    if (idx >= B_IMG * 169) return;
    const int b   = idx / 169;
    const int pos = idx % 169;
    const int py = pos / 13, px = pos % 13;

    const float* xp = x + (size_t)b * 784 + (2 * py) * 28 + 2 * px;
    float p[4][4];
#pragma unroll
    for (int r = 0; r < 4; ++r)
#pragma unroll
        for (int c = 0; c < 4; ++c) p[r][c] = xp[r * 28 + c];

    float* hb = h1 + (size_t)b * 8480 + pos;
    if (pos < 30) h1[(size_t)b * 8480 + 8450 + pos] = 0.f;   // zero pad cols

    for (int oc = 0; oc < 50; ++oc) {
        const float* wp = &ws[oc * 9];
        const float w00 = wp[0], w01 = wp[1], w02 = wp[2];
        const float w10 = wp[3], w11 = wp[4], w12 = wp[5];
        const float w20 = wp[6], w21 = wp[7], w22 = wp[8];
        float a[2][2];
#pragma unroll
        for (int dy = 0; dy < 2; ++dy)
#pragma unroll
            for (int dx = 0; dx < 2; ++dx) {
                a[dy][dx] = p[dy + 0][dx + 0] * w00 + p[dy + 0][dx + 1] * w01 + p[dy + 0][dx + 2] * w02
                          + p[dy + 1][dx + 0] * w10 + p[dy + 1][dx + 1] * w11 + p[dy + 1][dx + 2] * w12
                          + p[dy + 2][dx + 0] * w20 + p[dy + 2][dx + 1] * w21 + p[dy + 2][dx + 2] * w22;
            }
        float v = fmaxf(fmaxf(a[0][0], a[0][1]), fmaxf(a[1][0], a[1][1])) + bs[oc];
        hb[oc * 169] = fmaxf(v, 0.f);
    }
}

__device__ void role_wb16(int blk, const float* __restrict__ src,
                          bf16_t* __restrict__ dst, int N, int K, int Kp, int total)
{
    const int idx = blk * 256 + threadIdx.x;
    if (idx >= total) return;
    const int n = idx / Kp, k = idx % Kp;
    const float v = (n < N && k < K) ? src[(size_t)n * K + k] : 0.f;
    dst[idx] = (bf16_t)v;
}

__device__ void role_w2t(int blk, const float* __restrict__ w2, float* __restrict__ w2p)
{
    const int idx = blk * 256 + threadIdx.x;
    if (idx >= 50 * 600) return;
    const int ic = idx / 600, r = idx % 600, oc = r / 12, j = r % 12;
    w2p[idx] = (j < 9) ? w2[oc * 450 + ic * 9 + j] : 0.f;
}

// conv2 (50->50) + relu + pool; block per image, thread = 5 oc x 1 pooled pos.
// r11-proven structure: in[2][680] + wbuf[2][2400] double-buffered 4-ic
// chunks, direct global->LDS staging, one barrier per chunk (24640 B LDS).
// Round-14 change: ic processed in PAIRS (pa/pb) so both channels' 32
// p-loads issue before the 360-FMA burst -> half the exposed LDS latency.
// Per-acc[j][q] contribution order is still ic = 0,1,2,...,49 (for each j,
// pa's taps are added before pb's) with the verbatim 9-term expression ->
// h2 bit-identical to r8..r11 -> exit2 argmax parity.
__device__ void role_conv2(char* smem, int b,
    const float* __restrict__ h1, const float* __restrict__ w2p,
    const float* __restrict__ b2, float* __restrict__ h2)
{
    float* in   = (float*)smem;          // [2][680]
    float* wbuf = in + 1360;             // [2][2400], 16B-aligned (1360*4=5440)
    const int t = threadIdx.x;

    // stage chunk 0 (ic 0..3): input + weights
    for (int s = t; s < 676; s += 256) in[s] = h1[(size_t)b * 8480 + s];
    {
        const float4* src = (const float4*)w2p;
        float4* dst = (float4*)wbuf;
        for (int s = t; s < 600; s += 256) dst[s] = src[s];
    }
    __syncthreads();
    if (t < 30) h2[(size_t)b * 1280 + 1250 + t] = 0.f;

    const int ocg = t / 25;
    const int pos = t % 25;
    const int py = pos / 5, px = pos % 5;
    const int oc0 = ocg * 5;
    const bool act = (t < 250);

    float acc[5][4];
#pragma unroll
    for (int j = 0; j < 5; ++j)
#pragma unroll
        for (int q = 0; q < 4; ++q) acc[j][q] = 0.f;

    for (int ic0 = 0; ic0 < 50; ic0 += 4) {
        const int cur = (ic0 >> 2) & 1;
        if (ic0 + 4 < 50) {           // prefetch next <=4-ic chunk (input+weights)
            const int nxt = cur ^ 1;
            const int nic2 = (50 - ic0 - 4 < 4) ? (50 - ic0 - 4) : 4;
            for (int s = t; s < nic2 * 169; s += 256)
                in[nxt * 680 + s] = h1[(size_t)b * 8480 + (ic0 + 4) * 169 + s];
            const float4* src = (const float4*)(w2p + (size_t)(ic0 + 4) * 600);
            float4* dst = (float4*)(wbuf + nxt * 2400);
            for (int s = t; s < nic2 * 150; s += 256) dst[s] = src[s];
        }
        if (act) {
            const int nic = (50 - ic0 < 4) ? (50 - ic0) : 4;   // 4 or 2: even
            const float* ibc = in + cur * 680 + (2 * py) * 13 + 2 * px;
            const float* wcb = wbuf + cur * 2400 + oc0 * 12;
            for (int icl = 0; icl < nic; icl += 2) {
                float pa[4][4], pb[4][4];
                const float* ipa = ibc + icl * 169;
                const float* ipb = ipa + 169;
#pragma unroll
                for (int r = 0; r < 4; ++r)
#pragma unroll
                    for (int c = 0; c < 4; ++c) {
                        pa[r][c] = ipa[r * 13 + c];
                        pb[r][c] = ipb[r * 13 + c];
                    }
                const float* wla = wcb + icl * 600;
                const float* wlb = wla + 600;
#pragma unroll
                for (int j = 0; j < 5; ++j) {
                    {   // ic = ic0 + icl  (added first -> order preserved)
                        const f32x4 wv0 = *(const f32x4*)(wla + j * 12);
                        const f32x4 wv1 = *(const f32x4*)(wla + j * 12 + 4);
                        const f32x4 wv2 = *(const f32x4*)(wla + j * 12 + 8);
                        const float w00 = wv0[0], w01 = wv0[1], w02 = wv0[2];
                        const float w10 = wv0[3], w11 = wv1[0], w12 = wv1[1];
                        const float w20 = wv1[2], w21 = wv1[3], w22 = wv2[0];
#pragma unroll
                        for (int dy = 0; dy < 2; ++dy)
#pragma unroll
                            for (int dx = 0; dx < 2; ++dx) {
                                acc[j][dy * 2 + dx] +=
                                      pa[dy + 0][dx + 0] * w00 + pa[dy + 0][dx + 1] * w01 + pa[dy + 0][dx + 2] * w02
                                    + pa[dy + 1][dx + 0] * w10 + pa[dy + 1][dx + 1] * w11 + pa[dy + 1][dx + 2] * w12
                                    + pa[dy + 2][dx + 0] * w20 + pa[dy + 2][dx + 1] * w21 + pa[dy + 2][dx + 2] * w22;
                            }
                    }
                    {   // ic = ic0 + icl + 1 (added second)
                        const f32x4 wv0 = *(const f32x4*)(wlb + j * 12);
                        const f32x4 wv1 = *(const f32x4*)(wlb + j * 12 + 4);
                        const f32x4 wv2 = *(const f32x4*)(wlb + j * 12 + 8);
                        const float w00 = wv0[0], w01 = wv0[1], w02 = wv0[2];
                        const float w10 = wv0[3], w11 = wv1[0], w12 = wv1[1];
                        const float w20 = wv1[2], w21 = wv1[3], w22 = wv2[0];
#pragma unroll
                        for (int dy = 0; dy < 2; ++dy)
#pragma unroll
                            for (int dx = 0; dx < 2; ++dx) {
                                acc[j][dy * 2 + dx] +=
                                      pb[dy + 0][dx + 0] * w00 + pb[dy + 0][dx + 1] * w01 + pb[dy + 0][dx + 2] * w02
                                    + pb[dy + 1][dx + 0] * w10 + pb[dy + 1][dx + 1] * w11 + pb[dy + 1][dx + 2] * w12
                                    + pb[dy + 2][dx + 0] * w20 + pb[dy + 2][dx + 1] * w21 + pb[dy + 2][dx + 2] * w22;
                            }
                    }
                }
            }
        }
        __syncthreads();
    }

    if (act) {
#pragma unroll
        for (int j = 0; j < 5; ++j) {
            float v = fmaxf(fmaxf(acc[j][0], acc[j][1]), fmaxf(acc[j][2], acc[j][3]));
            h2[(size_t)b * 1280 + (oc0 + j) * 25 + pos] = fmaxf(v + b2[oc0 + j], 0.f);
        }
    }
}

// conv3 + relu + pool + FOLDED exit2. 4 img/block; wave il == image il,
// so exit2 is a pure shuffle reduce (no barrier, no LDS).
__device__ void role_conv3x(char* smem, int blk,
    const float* __restrict__ h2, const float* __restrict__ w3,
    const float* __restrict__ b3,
    const float* __restrict__ d2w, const float* __restrict__ d2b,
    int* __restrict__ e2, float* __restrict__ f3)
{
    float* in = (float*)smem;    // 5000
    const int t = threadIdx.x;
    for (int i = t; i < 5000; i += 256) {
        const int img = i / 1250, off = i % 1250;
        in[i] = h2[(size_t)(blk * 4 + img) * 1280 + off];
    }
    __syncthreads();
    const int il   = t >> 6;
    const int lane = t & 63;

    // folded exit2: one wave per image, strided dot + shuffle tree
    {
        const float* ip = &in[il * 1250];
        float s0 = 0.f, s1 = 0.f;
        for (int i = lane; i < 1250; i += 64) {
            const float vv = ip[i];
            s0 += vv * d2w[i];
            s1 += vv * d2w[1250 + i];
        }
#pragma unroll
        for (int off = 32; off > 0; off >>= 1) {
            s0 += __shfl_down(s0, off);
            s1 += __shfl_down(s1, off);
        }
        if (lane == 0) e2[blk * 4 + il] = (s0 + d2b[0] >= s1 + d2b[1]) ? 1 : 0;
    }

    const int oc = lane;
    if (oc >= 50) return;

    const float* ip0 = &in[il * 1250];
    float a00 = 0.f, a01 = 0.f, a10 = 0.f, a11 = 0.f;
    for (int ic = 0; ic < 50; ++ic) {
        float p[4][4];
        const float* ip = ip0 + ic * 25;
#pragma unroll
        for (int r = 0; r < 4; ++r)
#pragma unroll
            for (int c = 0; c < 4; ++c) p[r][c] = ip[r * 5 + c];
        const float* wp = &w3[((size_t)oc * 50 + ic) * 9];
        const float w00 = wp[0], w01 = wp[1], w02 = wp[2];
        const float w10 = wp[3], w11 = wp[4], w12 = wp[5];
        const float w20 = wp[6], w21 = wp[7], w22 = wp[8];
        a00 += p[0][0]*w00 + p[0][1]*w01 + p[0][2]*w02 + p[1][0]*w10 + p[1][1]*w11 + p[1][2]*w12 + p[2][0]*w20 + p[2][1]*w21 + p[2][2]*w22;
        a01 += p[0][1]*w00 + p[0][2]*w01 + p[0][3]*w02 + p[1][1]*w10 + p[1][2]*w11 + p[1][3]*w12 + p[2][1]*w20 + p[2][2]*w21 + p[2][3]*w22;
        a10 += p[1][0]*w00 + p[1][1]*w01 + p[1][2]*w02 + p[2][0]*w10 + p[2][1]*w11 + p[2][2]*w12 + p[3][0]*w20 + p[3][1]*w21 + p[3][2]*w22;
        a11 += p[1][1]*w00 + p[1][2]*w01 + p[1][3]*w02 + p[2][1]*w10 + p[2][2]*w11 + p[2][3]*w12 + p[3][1]*w20 + p[3][2]*w21 + p[3][3]*w22;
    }
    float v = fmaxf(fmaxf(a00, a01), fmaxf(a10, a11)) + b3[oc];
    f3[(size_t)(blk * 4 + il) * 50 + oc] = fmaxf(v, 0.f);
}

__device__ void role_exit(char* smem, int b,
    const float* __restrict__ F, int ldf, int K,
    const float* __restrict__ dw, const float* __restrict__ db, int* __restrict__ e)
{
    float* r0 = (float*)smem;   // 256
    float* r1 = r0 + 256;       // 256
    const int t = threadIdx.x;
    const float* f = F + (size_t)b * ldf;
    float s0 = 0.f, s1 = 0.f;
    for (int i = t; i < K; i += 256) {
        const float v = f[i];
        s0 += v * dw[i];
        s1 += v * dw[K + i];
    }
    r0[t] = s0; r1[t] = s1;
    __syncthreads();
    for (int s = 128; s > 0; s >>= 1) {
        if (t < s) { r0[t] += r0[t + s]; r1[t] += r1[t + s]; }
        __syncthreads();
    }
    if (t == 0) e[b] = (r0[0] + db[0] >= r1[0] + db[1]) ? 1 : 0;
}

// MFMA GEMM split-K=2 (r9-proven). g in [0,512): bx=g&31, by=(g>>5)&7, kz=g>>8.
__device__ void role_gemm(char* smem, int g,
    const float* __restrict__ A, int lda, const bf16_t* __restrict__ W,
    const float* __restrict__ bias, float* __restrict__ C0, float* __restrict__ C1,
    int Kp, int khalf, int Nout, int ldc)
{
    bf16_t* As = (bf16_t*)smem;      // 128*40
    bf16_t* Bs = As + 128 * 40;      // 64*40

    const int t = threadIdx.x;
    const int m0 = (g & 31) * 128;
    const int n0 = ((g >> 5) & 7) * 64;
    const int kz = g >> 8;
    const int kbeg = kz ? khalf : 0;
    const int kend = kz ? Kp : khalf;
    float* C = kz ? C1 : C0;

    const int wave = t >> 6;
    const int lane = t & 63;
    const int wm = (wave >> 1) * 64;
    const int wn = (wave & 1) * 32;
    const int quad = lane >> 4;
    const int lr = lane & 15;

    f32x4 acc[4][2];
#pragma unroll
    for (int i = 0; i < 4; ++i)
#pragma unroll
        for (int j = 0; j < 2; ++j) acc[i][j] = (f32x4)0.f;

    const int ar = t >> 2;
    const int ac = (t & 3) * 8;

    for (int k0 = kbeg; k0 < kend; k0 += 32) {
        __syncthreads();
#pragma unroll
        for (int h = 0; h < 2; ++h) {
            const float* ap = A + (size_t)(m0 + ar + h * 64) * lda + k0 + ac;
            const float4 f0 = *(const float4*)ap;
            const float4 f1 = *(const float4*)(ap + 4);
            bf16x8 v;
            v[0] = (bf16_t)f0.x; v[1] = (bf16_t)f0.y; v[2] = (bf16_t)f0.z; v[3] = (bf16_t)f0.w;
            v[4] = (bf16_t)f1.x; v[5] = (bf16_t)f1.y; v[6] = (bf16_t)f1.z; v[7] = (bf16_t)f1.w;
            *(bf16x8*)&As[(ar + h * 64) * 40 + ac] = v;
        }
        *(uint4*)&Bs[ar * 40 + ac] = *(const uint4*)&W[(size_t)(n0 + ar) * Kp + k0 + ac];
        __syncthreads();

        bf16x8 af[4], bfr[2];
#pragma unroll
        for (int i = 0; i < 4; ++i)
            af[i] = *(const bf16x8*)&As[(wm + i * 16 + lr) * 40 + quad * 8];
#pragma unroll
        for (int j = 0; j < 2; ++j)
            bfr[j] = *(const bf16x8*)&Bs[(wn + j * 16 + lr) * 40 + quad * 8];
#pragma unroll
        for (int i = 0; i < 4; ++i)
#pragma unroll
            for (int j = 0; j < 2; ++j)
                acc[i][j] = __builtin_amdgcn_mfma_f32_16x16x32_bf16(af[i], bfr[j], acc[i][j], 0, 0, 0);
    }

#pragma unroll
    for (int j = 0; j < 2; ++j) {
        const int n = n0 + wn + j * 16 + lr;
        const float bv = (kz == 0 && n < Nout) ? bias[n] : 0.f;
#pragma unroll
        for (int i = 0; i < 4; ++i) {
            const int mrow = m0 + wm + i * 16 + quad * 4;
#pragma unroll
            for (int r = 0; r < 4; ++r)
                C[(size_t)(mrow + r) * ldc + n] = acc[i][j][r] + bv;
        }
    }
}

// lin10: out[b,o<10] = (U[+U2]) @ W^T + bias; 16 img x 16 k-strips per block.
__device__ void role_lin10(char* smem, int blk,
    const float* __restrict__ U, const float* __restrict__ U2, int ldu,
    const float* __restrict__ W, const float* __restrict__ bias,
    float* __restrict__ out)
{
    float* red = (float*)smem;   // [16][10][17]
    const int t = threadIdx.x;
    const int ks = t & 15;
    const int il = t >> 4;
    const int b  = blk * 16 + il;
    const float* u = U + (size_t)b * ldu;

    float acc[10];
#pragma unroll
    for (int o = 0; o < 10; ++o) acc[o] = 0.f;

    if (U2) {
        const float* u2 = U2 + (size_t)b * ldu;
        for (int i = 0; i < 31; ++i) {
            const int k = ks + i * 16;
            const float uv = u[k] + u2[k];
#pragma unroll
            for (int o = 0; o < 10; ++o) acc[o] += uv * W[o * 500 + k];
        }
        const int k = ks + 496;
        if (k < 500) {
            const float uv = u[k] + u2[k];
#pragma unroll
            for (int o = 0; o < 10; ++o) acc[o] += uv * W[o * 500 + k];
        }
    } else {
        for (int i = 0; i < 31; ++i) {
            const int k = ks + i * 16;
            const float uv = u[k];
#pragma unroll
            for (int o = 0; o < 10; ++o) acc[o] += uv * W[o * 500 + k];
        }
        const int k = ks + 496;
        if (k < 500) {
            const float uv = u[k];
#pragma unroll
            for (int o = 0; o < 10; ++o) acc[o] += uv * W[o * 500 + k];
        }
    }
#pragma unroll
    for (int o = 0; o < 10; ++o) red[(il * 10 + o) * 17 + ks] = acc[o];
    __syncthreads();
    if (t < 160) {
        const int il2 = t / 10, o = t - il2 * 10;
        float s = 0.f;
#pragma unroll
        for (int q = 0; q < 16; ++q) s += red[(il2 * 10 + o) * 17 + q];
        out[(size_t)(blk * 16 + il2) * 10 + o] = s + bias[o];
    }
}

// ============================ fused kernels ================================

__global__ __launch_bounds__(256) void k_prep(
    const float* x, const float* c1w, const float* c1b, float* h1,
    const float* l1c1w, bf16_t* Wb1, const float* l1c2w, bf16_t* Wb2,
    const float* c2w, float* w2p)
{
    extern __shared__ char smem[];
    const int g = blockIdx.x;
    if (g < 2704)        role_conv1(smem, g, x, c1w, c1b, h1);
    else if (g < 19664)  role_wb16(g - 2704, l1c1w, Wb1, 500, 8450, 8480, 512 * 8480);
    else if (g < 22224)  role_wb16(g - 19664, l1c2w, Wb2, 500, 1250, 1280, 512 * 1280);
    else                 role_w2t(g - 22224, c2w, w2p);
}

__global__ __launch_bounds__(256) void k_stage1(
    const float* h1, const bf16_t* Wb1, const float* l1c1b, float* u, float* up,
    const float* d1w, const float* d1b, int* e1,
    const float* w2p, const float* c2b, float* h2)
{
    extern __shared__ char smem[];
    const int g = blockIdx.x;
    if (g < 512)         role_gemm(smem, g, h1, 8480, Wb1, l1c1b, u, up, 8480, 4256, 500, 512);
    else if (g < 4608)   role_conv2(smem, g - 512, h1, w2p, c2b, h2);
    else                 role_exit(smem, g - 4608, h1, 8480, 8450, d1w, d1b, e1);
}

__global__ __launch_bounds__(256) void k_stage2(
    const float* h2, const bf16_t* Wb2, const float* l1c2b, float* v, float* vp,
    const float* d2w, const float* d2b, int* e2,
    const float* c3w, const float* c3b, float* f3,
    const float* u, const float* up, const float* l2c1w, const float* l2c1b, float* out1)
{
    extern __shared__ char smem[];
    const int g = blockIdx.x;
    if (g < 512)         role_gemm(smem, g, h2, 1280, Wb2, l1c2b, v, vp, 1280, 640, 500, 512);
    else if (g < 1536)   role_conv3x(smem, g - 512, h2, c3w, c3b, d2w, d2b, e2, f3);
    else                 role_lin10(smem, g - 1536, u, up, 512, l2c1w, l2c1b, out1);
}

// k_tail: per block = 16 samples. lin10-2 (v/vp) -> o2loc; lin500 -> u3 LDS;
// lin10-3 (u3 LDS) -> o3loc; select + log_softmax -> out. FP per-(b,o)
// expressions identical to round 10's separate kernels.
__global__ __launch_bounds__(256) void k_tail(
    const float* __restrict__ v, const float* __restrict__ vp,
    const float* __restrict__ l2c2w, const float* __restrict__ l2c2b,
    const float* __restrict__ f3, const float* __restrict__ l1w, const float* __restrict__ l1b,
    const float* __restrict__ l2w, const float* __restrict__ l2b,
    const float* __restrict__ out1, const int* __restrict__ e1, const int* __restrict__ e2,
    float* __restrict__ out)
{
    __shared__ float fs[800];        // 16 x 50
    __shared__ float u3loc[8000];    // 16 x 500
    __shared__ float red[2720];      // 16 x 10 x 17
    __shared__ float o2loc[160];
    __shared__ float o3loc[160];

    const int t   = threadIdx.x;
    const int blk = blockIdx.x;
    const int ks  = t & 15;
    const int il  = t >> 4;

    // stage f3 for 16 images
    for (int i = t; i < 800; i += 256) fs[i] = f3[(size_t)blk * 800 + i];
    __syncthreads();

    // lin500 -> u3loc (same per-(b,o) expression as round 10's role_lin500)
    for (int im = 0; im < 16; ++im) {
        for (int o = t; o < 500; o += 256) {
            float s = 0.f;
#pragma unroll
            for (int k = 0; k < 50; ++k) s += fs[im * 50 + k] * l1w[o * 50 + k];
            u3loc[im * 500 + o] = fmaxf(s + l1b[o], 0.f);
        }
    }

    // lin10-2 from v/vp (global, ldu=512)
    {
        const float* uu  = v  + (size_t)(blk * 16 + il) * 512;
        const float* uu2 = vp + (size_t)(blk * 16 + il) * 512;
        float acc[10];
#pragma unroll
        for (int o = 0; o < 10; ++o) acc[o] = 0.f;
        for (int i = 0; i < 31; ++i) {
            const int k = ks + i * 16;
            const float uv = uu[k] + uu2[k];
#pragma unroll
            for (int o = 0; o < 10; ++o) acc[o] += uv * l2c2w[o * 500 + k];
        }
        const int k = ks + 496;
        if (k < 500) {
            const float uv = uu[k] + uu2[k];
#pragma unroll
            for (int o = 0; o < 10; ++o) acc[o] += uv * l2c2w[o * 500 + k];
        }
        __syncthreads();   // u3loc writes done; red free to use
#pragma unroll
        for (int o = 0; o < 10; ++o) red[(il * 10 + o) * 17 + ks] = acc[o];
        __syncthreads();
        if (t < 160) {
            const int il2 = t / 10, o = t - il2 * 10;
            float s = 0.f;
#pragma unroll
            for (int q = 0; q < 16; ++q) s += red[(il2 * 10 + o) * 17 + q];
            o2loc[t] = s + l2c2b[o];
        }
        __syncthreads();
    }

    // lin10-3 from u3loc (LDS, ldu=500)
    {
        const float* uu = u3loc + il * 500;
        float acc[10];
#pragma unroll
        for (int o = 0; o < 10; ++o) acc[o] = 0.f;
        for (int i = 0; i < 31; ++i) {
            const int k = ks + i * 16;
            const float uv = uu[k];
#pragma unroll
            for (int o = 0; o < 10; ++o) acc[o] += uv * l2w[o * 500 + k];
        }
        const int k = ks + 496;
        if (k < 500) {
            const float uv = uu[k];
#pragma unroll
            for (int o = 0; o < 10; ++o) acc[o] += uv * l2w[o * 500 + k];
        }
#pragma unroll
        for (int o = 0; o < 10; ++o) red[(il * 10 + o) * 17 + ks] = acc[o];
        __syncthreads();
        if (t < 160) {
            const int il2 = t / 10, o = t - il2 * 10;
            float s = 0.f;
#pragma unroll
            for (int q = 0; q < 16; ++q) s += red[(il2 * 10 + o) * 17 + q];
            o3loc[t] = s + l2b[o];
        }
        __syncthreads();
    }

    // select + log_softmax (one thread per sample)
    if (t < 16) {
        const int b = blk * 16 + t;
        float vv[10];
        if (e1[b]) {
            const float* src = out1 + (size_t)b * 10;
#pragma unroll
            for (int o = 0; o < 10; ++o) vv[o] = src[o];
        } else if (e2[b]) {
#pragma unroll
            for (int o = 0; o < 10; ++o) vv[o] = o2loc[t * 10 + o];
        } else {
#pragma unroll
            for (int o = 0; o < 10; ++o) vv[o] = o3loc[t * 10 + o];
        }
        float m = -3.4e38f;
#pragma unroll
        for (int o = 0; o < 10; ++o) m = fmaxf(m, vv[o]);
        float s = 0.f;
#pragma unroll
        for (int o = 0; o < 10; ++o) s += expf(vv[o] - m);
        const float ls = logf(s);
#pragma unroll
        for (int o = 0; o < 10; ++o) out[(size_t)b * 10 + o] = vv[o] - m - ls;
    }
}

// ---------------------------------------------------------------------------
static inline size_t align256(size_t v) { return (v + 255) & ~(size_t)255; }

extern "C" void kernel_launch(void* const* d_in, const int* in_sizes, int n_in,
                              void* d_out, int out_size, void* d_ws, size_t ws_size,
                              hipStream_t stream)
{
    const float* x     = (const float*)d_in[0];
    const float* c1w   = (const float*)d_in[1];
    const float* c1b   = (const float*)d_in[2];
    const float* c2w   = (const float*)d_in[3];
    const float* c2b   = (const float*)d_in[4];
    const float* c3w   = (const float*)d_in[5];
    const float* c3b   = (const float*)d_in[6];
    const float* l1c1w = (const float*)d_in[7];
    const float* l1c1b = (const float*)d_in[8];
    const float* l2c1w = (const float*)d_in[9];
    const float* l2c1b = (const float*)d_in[10];
    const float* l1c2w = (const float*)d_in[11];
    const float* l1c2b = (const float*)d_in[12];
    const float* l2c2w = (const float*)d_in[13];
    const float* l2c2b = (const float*)d_in[14];
    const float* l1w   = (const float*)d_in[15];
    const float* l1b   = (const float*)d_in[16];
    const float* l2w   = (const float*)d_in[17];
    const float* l2b   = (const float*)d_in[18];
    const float* d1w   = (const float*)d_in[19];
    const float* d1b   = (const float*)d_in[20];
    const float* d2w   = (const float*)d_in[21];
    const float* d2b   = (const float*)d_in[22];

    // ---- workspace layout (single chunk, B=4096; fits r9/r10-proven budget)
    size_t off = 0;
    const size_t oWb1  = off; off = align256(off + (size_t)512 * 8480 * 2);
    const size_t oWb2  = off; off = align256(off + (size_t)512 * 1280 * 2);
    const size_t oW2P  = off; off = align256(off + (size_t)50 * 600 * 4);
    const size_t oOut1 = off; off = align256(off + (size_t)B_IMG * 10 * 4);
    const size_t oE1   = off; off = align256(off + (size_t)B_IMG * 4);
    const size_t oE2   = off; off = align256(off + (size_t)B_IMG * 4);
    const size_t oH1   = off; off = align256(off + (size_t)B_IMG * 8480 * 4);
    const size_t oH2   = off; off = align256(off + (size_t)B_IMG * 1280 * 4);
    const size_t oU    = off; off = align256(off + (size_t)B_IMG * 512 * 4);
    const size_t oUP   = off; off = align256(off + (size_t)B_IMG * 512 * 4);
    const size_t oF3   = off; off = align256(off + (size_t)B_IMG * 50 * 4);

    char* ws = (char*)d_ws;
    bf16_t* Wb1  = (bf16_t*)(ws + oWb1);
    bf16_t* Wb2  = (bf16_t*)(ws + oWb2);
    float*  w2p  = (float*) (ws + oW2P);
    float*  out1 = (float*) (ws + oOut1);
    int*    e1   = (int*)   (ws + oE1);
    int*    e2   = (int*)   (ws + oE2);
    float*  h1   = (float*) (ws + oH1);
    float*  h2   = (float*) (ws + oH2);
    float*  u    = (float*) (ws + oU);
    float*  up   = (float*) (ws + oUP);
    float*  f3   = (float*) (ws + oF3);
    // stage-2 gemm outputs carved from the dead h1 region
    float*  v    = h1;                          // 4096*512 f32
    float*  vp   = h1 + (size_t)B_IMG * 512;    // 4096*512 f32

    float* out = (float*)d_out;

    // P: conv1 + weight conversions (all independent)
    k_prep<<<22342, 256, 2048, stream>>>(x, c1w, c1b, h1, l1c1w, Wb1, l1c2w, Wb2, c2w, w2p);
    // A: gemm1 | conv2 | exit1  (consume h1); r11-proven split, LDS 24832
    k_stage1<<<8704, 256, 24832, stream>>>(h1, Wb1, l1c1b, u, up, d1w, d1b, e1, w2p, c2b, h2);
    // C: gemm2 | conv3+exit2 | lin10-1  (consume h2 / stage1-u)
    k_stage2<<<1792, 256, 20000, stream>>>(h2, Wb2, l1c2b, v, vp, d2w, d2b, e2,
                                           c3w, c3b, f3, u, up, l2c1w, l2c1b, out1);
    // T: lin10-2 | lin500 | lin10-3 | select  (per-16-sample blocks)
    k_tail<<<256, 256, 0, stream>>>(v, vp, l2c2w, l2c2b, f3, l1w, l1b, l2w, l2b,
                                    out1, e1, e2, out);

    (void)in_sizes; (void)n_in; (void)out_size; (void)ws_size;
}

// Round 4
// 712.225 us; speedup vs baseline: 1.3795x; 1.0562x over previous
//
#include <hip/hip_runtime.h>
#include <hip/hip_bf16.h>
#include <cstdint>

// ---------------------------------------------------------------------------
// ThreeLayerCNN (BranchyNet early-exit), B=4096.
// Precision: conv1/conv2/exit1/exit2 fp32 (argmax parity with numpy ref);
// big FC GEMMs (l1c1, l1c2) bf16 MFMA w/ fp32 accum (output tol 0.146).
// Round 15 (post-mortems: r12 spill disaster; r13 exit-fold removed the
// latency-filler blocks; r14 ic-pair unroll neutral -> conv2 micro-opts
// exhausted, revert to byte-exact r11 conv2):
//  - NEW: producers write bf16 mirrors of the GEMM A-operands ONCE.
//    conv1 -> h1b (69 MB), conv2 -> h2b (10.5 MB). role_gemm A-staging
//    becomes a bare uint4 copy: kills the 16x-redundant fp32->bf16
//    cvt/pack chains (~4.4e9 lane-ops in k_stage1) and halves A-fetch
//    bytes. Same RNE cast as before -> GEMM bit-identical.
//  - role_wb16 vectorized x8 (scalar bf16 stores were Common-mistake #2);
//    k_prep grid 22342 -> 5262.
//  - conv2/conv3x/exits/lin10/tail byte-identical math to r11/r13 kernels.
// ---------------------------------------------------------------------------

typedef __bf16 bf16_t;
typedef __bf16 bf16x8 __attribute__((ext_vector_type(8)));
typedef float  f32x4  __attribute__((ext_vector_type(4)));

#define B_IMG 4096

// ======================= role bodies (device functions) =====================

__device__ void role_conv1(char* smem, int blk,
    const float* __restrict__ x, const float* __restrict__ w1,
    const float* __restrict__ b1, float* __restrict__ h1,
    bf16_t* __restrict__ h1b)
{
    float* ws = (float*)smem;        // 450
    float* bs = ws + 456;            // 50
    const int t = threadIdx.x;
    for (int i = t; i < 450; i += 256) ws[i] = w1[i];
    if (t < 50) bs[t] = b1[t];
    __syncthreads();

    const int idx = blk * 256 + t;
    if (idx >= B_IMG * 169) return;
    const int b   = idx / 169;
    const int pos = idx % 169;
    const int py = pos / 13, px = pos % 13;

    const float* xp = x + (size_t)b * 784 + (2 * py) * 28 + 2 * px;
    float p[4][4];
#pragma unroll
    for (int r = 0; r < 4; ++r)
#pragma unroll
        for (int c = 0; c < 4; ++c) p[r][c] = xp[r * 28 + c];

    float*  hb  = h1  + (size_t)b * 8480 + pos;
    bf16_t* hbb = h1b + (size_t)b * 8480 + pos;
    if (pos < 30) {
        h1 [(size_t)b * 8480 + 8450 + pos] = 0.f;            // zero pad cols
        h1b[(size_t)b * 8480 + 8450 + pos] = (bf16_t)0.f;
    }

    for (int oc = 0; oc < 50; ++oc) {
        const float* wp = &ws[oc * 9];
        const float w00 = wp[0], w01 = wp[1], w02 = wp[2];
        const float w10 = wp[3], w11 = wp[4], w12 = wp[5];
        const float w20 = wp[6], w21 = wp[7], w22 = wp[8];
        float a[2][2];
#pragma unroll
        for (int dy = 0; dy < 2; ++dy)
#pragma unroll
            for (int dx = 0; dx < 2; ++dx) {
                a[dy][dx] = p[dy + 0][dx + 0] * w00 + p[dy + 0][dx + 1] * w01 + p[dy + 0][dx + 2] * w02
                          + p[dy + 1][dx + 0] * w10 + p[dy + 1][dx + 1] * w11 + p[dy + 1][dx + 2] * w12
                          + p[dy + 2][dx + 0] * w20 + p[dy + 2][dx + 1] * w21 + p[dy + 2][dx + 2] * w22;
            }
        float v = fmaxf(fmaxf(a[0][0], a[0][1]), fmaxf(a[1][0], a[1][1])) + bs[oc];
        const float r = fmaxf(v, 0.f);
        hb [oc * 169] = r;
        hbb[oc * 169] = (bf16_t)r;      // same RNE cast the gemm used to do
    }
}

// x8-vectorized fp32 -> bf16 weight conversion (pad cols/rows zeroed).
__device__ void role_wb16v8(int blk, const float* __restrict__ src,
                            bf16_t* __restrict__ dst, int N, int K, int Kp, int totalv)
{
    const int idx = blk * 256 + threadIdx.x;     // one thread per 8-elem group
    if (idx >= totalv) return;
    const int kg = Kp >> 3;
    const int n  = idx / kg;
    const int k0 = (idx - n * kg) * 8;
    bf16x8 v;
#pragma unroll
    for (int i = 0; i < 8; ++i) {
        const int k = k0 + i;
        const float f = (n < N && k < K) ? src[(size_t)n * K + k] : 0.f;
        v[i] = (bf16_t)f;
    }
    *(bf16x8*)&dst[(size_t)n * Kp + k0] = v;
}

__device__ void role_w2t(int blk, const float* __restrict__ w2, float* __restrict__ w2p)
{
    const int idx = blk * 256 + threadIdx.x;
    if (idx >= 50 * 600) return;
    const int ic = idx / 600, r = idx % 600, oc = r / 12, j = r % 12;
    w2p[idx] = (j < 9) ? w2[oc * 450 + ic * 9 + j] : 0.f;
}

// conv2 (50->50) + relu + pool; block per image, thread = 5 oc x 1 pooled pos.
// BYTE-EXACT r11 structure (469 us proven): in[2][680] + wbuf[2][2400]
// double-buffered 4-ic chunks, direct global->LDS staging, one barrier per
// chunk. Only addition: bf16 mirror stores of h2 (h2b) in the epilogue.
__device__ void role_conv2(char* smem, int b,
    const float* __restrict__ h1, const float* __restrict__ w2p,
    const float* __restrict__ b2, float* __restrict__ h2,
    bf16_t* __restrict__ h2b)
{
    float* in   = (float*)smem;          // [2][680]
    float* wbuf = in + 1360;             // [2][2400], 16B-aligned (1360*4=5440)
    const int t = threadIdx.x;

    // stage chunk 0 (ic 0..3): input + weights
    for (int s = t; s < 676; s += 256) in[s] = h1[(size_t)b * 8480 + s];
    {
        const float4* src = (const float4*)w2p;
        float4* dst = (float4*)wbuf;
        for (int s = t; s < 600; s += 256) dst[s] = src[s];
    }
    __syncthreads();
    if (t < 30) {
        h2 [(size_t)b * 1280 + 1250 + t] = 0.f;
        h2b[(size_t)b * 1280 + 1250 + t] = (bf16_t)0.f;
    }

    const int ocg = t / 25;
    const int pos = t % 25;
    const int py = pos / 5, px = pos % 5;
    const int oc0 = ocg * 5;
    const bool act = (t < 250);

    float acc[5][4];
#pragma unroll
    for (int j = 0; j < 5; ++j)
#pragma unroll
        for (int q = 0; q < 4; ++q) acc[j][q] = 0.f;

    for (int ic0 = 0; ic0 < 50; ic0 += 4) {
        const int cur = (ic0 >> 2) & 1;
        if (ic0 + 4 < 50) {           // prefetch next <=4-ic chunk (input+weights)
            const int nxt = cur ^ 1;
            const int nic2 = (50 - ic0 - 4 < 4) ? (50 - ic0 - 4) : 4;
            for (int s = t; s < nic2 * 169; s += 256)
                in[nxt * 680 + s] = h1[(size_t)b * 8480 + (ic0 + 4) * 169 + s];
            const float4* src = (const float4*)(w2p + (size_t)(ic0 + 4) * 600);
            float4* dst = (float4*)(wbuf + nxt * 2400);
            for (int s = t; s < nic2 * 150; s += 256) dst[s] = src[s];
        }
        if (act) {
            const int nic = (50 - ic0 < 4) ? (50 - ic0) : 4;
            const float* ibc = in + cur * 680 + (2 * py) * 13 + 2 * px;
            for (int icl = 0; icl < nic; ++icl) {
                float p[4][4];
                const float* ip = ibc + icl * 169;
#pragma unroll
                for (int r = 0; r < 4; ++r)
#pragma unroll
                    for (int c = 0; c < 4; ++c) p[r][c] = ip[r * 13 + c];
                const float* wl = wbuf + cur * 2400 + icl * 600 + oc0 * 12;
#pragma unroll
                for (int j = 0; j < 5; ++j) {
                    const f32x4 wv0 = *(const f32x4*)(wl + j * 12);
                    const f32x4 wv1 = *(const f32x4*)(wl + j * 12 + 4);
                    const f32x4 wv2 = *(const f32x4*)(wl + j * 12 + 8);
                    const float w00 = wv0[0], w01 = wv0[1], w02 = wv0[2];
                    const float w10 = wv0[3], w11 = wv1[0], w12 = wv1[1];
                    const float w20 = wv1[2], w21 = wv1[3], w22 = wv2[0];
#pragma unroll
                    for (int dy = 0; dy < 2; ++dy)
#pragma unroll
                        for (int dx = 0; dx < 2; ++dx) {
                            acc[j][dy * 2 + dx] +=
                                  p[dy + 0][dx + 0] * w00 + p[dy + 0][dx + 1] * w01 + p[dy + 0][dx + 2] * w02
                                + p[dy + 1][dx + 0] * w10 + p[dy + 1][dx + 1] * w11 + p[dy + 1][dx + 2] * w12
                                + p[dy + 2][dx + 0] * w20 + p[dy + 2][dx + 1] * w21 + p[dy + 2][dx + 2] * w22;
                        }
                }
            }
        }
        __syncthreads();
    }

    if (act) {
#pragma unroll
        for (int j = 0; j < 5; ++j) {
            float v = fmaxf(fmaxf(acc[j][0], acc[j][1]), fmaxf(acc[j][2], acc[j][3]));
            const float r = fmaxf(v + b2[oc0 + j], 0.f);
            h2 [(size_t)b * 1280 + (oc0 + j) * 25 + pos] = r;
            h2b[(size_t)b * 1280 + (oc0 + j) * 25 + pos] = (bf16_t)r;
        }
    }
}

// conv3 + relu + pool + FOLDED exit2. 4 img/block; wave il == image il,
// so exit2 is a pure shuffle reduce (no barrier, no LDS).
__device__ void role_conv3x(char* smem, int blk,
    const float* __restrict__ h2, const float* __restrict__ w3,
    const float* __restrict__ b3,
    const float* __restrict__ d2w, const float* __restrict__ d2b,
    int* __restrict__ e2, float* __restrict__ f3)
{
    float* in = (float*)smem;    // 5000
    const int t = threadIdx.x;
    for (int i = t; i < 5000; i += 256) {
        const int img = i / 1250, off = i % 1250;
        in[i] = h2[(size_t)(blk * 4 + img) * 1280 + off];
    }
    __syncthreads();
    const int il   = t >> 6;
    const int lane = t & 63;

    // folded exit2: one wave per image, strided dot + shuffle tree
    {
        const float* ip = &in[il * 1250];
        float s0 = 0.f, s1 = 0.f;
        for (int i = lane; i < 1250; i += 64) {
            const float vv = ip[i];
            s0 += vv * d2w[i];
            s1 += vv * d2w[1250 + i];
        }
#pragma unroll
        for (int off = 32; off > 0; off >>= 1) {
            s0 += __shfl_down(s0, off);
            s1 += __shfl_down(s1, off);
        }
        if (lane == 0) e2[blk * 4 + il] = (s0 + d2b[0] >= s1 + d2b[1]) ? 1 : 0;
    }

    const int oc = lane;
    if (oc >= 50) return;

    const float* ip0 = &in[il * 1250];
    float a00 = 0.f, a01 = 0.f, a10 = 0.f, a11 = 0.f;
    for (int ic = 0; ic < 50; ++ic) {
        float p[4][4];
        const float* ip = ip0 + ic * 25;
#pragma unroll
        for (int r = 0; r < 4; ++r)
#pragma unroll
            for (int c = 0; c < 4; ++c) p[r][c] = ip[r * 5 + c];
        const float* wp = &w3[((size_t)oc * 50 + ic) * 9];
        const float w00 = wp[0], w01 = wp[1], w02 = wp[2];
        const float w10 = wp[3], w11 = wp[4], w12 = wp[5];
        const float w20 = wp[6], w21 = wp[7], w22 = wp[8];
        a00 += p[0][0]*w00 + p[0][1]*w01 + p[0][2]*w02 + p[1][0]*w10 + p[1][1]*w11 + p[1][2]*w12 + p[2][0]*w20 + p[2][1]*w21 + p[2][2]*w22;
        a01 += p[0][1]*w00 + p[0][2]*w01 + p[0][3]*w02 + p[1][1]*w10 + p[1][2]*w11 + p[1][3]*w12 + p[2][1]*w20 + p[2][2]*w21 + p[2][3]*w22;
        a10 += p[1][0]*w00 + p[1][1]*w01 + p[1][2]*w02 + p[2][0]*w10 + p[2][1]*w11 + p[2][2]*w12 + p[3][0]*w20 + p[3][1]*w21 + p[3][2]*w22;
        a11 += p[1][1]*w00 + p[1][2]*w01 + p[1][3]*w02 + p[2][1]*w10 + p[2][2]*w11 + p[2][3]*w12 + p[3][1]*w20 + p[3][2]*w21 + p[3][3]*w22;
    }
    float v = fmaxf(fmaxf(a00, a01), fmaxf(a10, a11)) + b3[oc];
    f3[(size_t)(blk * 4 + il) * 50 + oc] = fmaxf(v, 0.f);
}

__device__ void role_exit(char* smem, int b,
    const float* __restrict__ F, int ldf, int K,
    const float* __restrict__ dw, const float* __restrict__ db, int* __restrict__ e)
{
    float* r0 = (float*)smem;   // 256
    float* r1 = r0 + 256;       // 256
    const int t = threadIdx.x;
    const float* f = F + (size_t)b * ldf;
    float s0 = 0.f, s1 = 0.f;
    for (int i = t; i < K; i += 256) {
        const float v = f[i];
        s0 += v * dw[i];
        s1 += v * dw[K + i];
    }
    r0[t] = s0; r1[t] = s1;
    __syncthreads();
    for (int s = 128; s > 0; s >>= 1) {
        if (t < s) { r0[t] += r0[t + s]; r1[t] += r1[t + s]; }
        __syncthreads();
    }
    if (t == 0) e[b] = (r0[0] + db[0] >= r1[0] + db[1]) ? 1 : 0;
}

// MFMA GEMM split-K=2 (r9-proven schedule). A is now PRE-CONVERTED bf16
// (h1b/h2b): staging is a bare uint4 copy, no cvt chain, half the bytes.
__device__ void role_gemm(char* smem, int g,
    const bf16_t* __restrict__ A, int lda, const bf16_t* __restrict__ W,
    const float* __restrict__ bias, float* __restrict__ C0, float* __restrict__ C1,
    int Kp, int khalf, int Nout, int ldc)
{
    bf16_t* As = (bf16_t*)smem;      // 128*40
    bf16_t* Bs = As + 128 * 40;      // 64*40

    const int t = threadIdx.x;
    const int m0 = (g & 31) * 128;
    const int n0 = ((g >> 5) & 7) * 64;
    const int kz = g >> 8;
    const int kbeg = kz ? khalf : 0;
    const int kend = kz ? Kp : khalf;
    float* C = kz ? C1 : C0;

    const int wave = t >> 6;
    const int lane = t & 63;
    const int wm = (wave >> 1) * 64;
    const int wn = (wave & 1) * 32;
    const int quad = lane >> 4;
    const int lr = lane & 15;

    f32x4 acc[4][2];
#pragma unroll
    for (int i = 0; i < 4; ++i)
#pragma unroll
        for (int j = 0; j < 2; ++j) acc[i][j] = (f32x4)0.f;

    const int ar = t >> 2;
    const int ac = (t & 3) * 8;

    for (int k0 = kbeg; k0 < kend; k0 += 32) {
        __syncthreads();
#pragma unroll
        for (int h = 0; h < 2; ++h) {
            *(uint4*)&As[(ar + h * 64) * 40 + ac] =
                *(const uint4*)&A[(size_t)(m0 + ar + h * 64) * lda + k0 + ac];
        }
        *(uint4*)&Bs[ar * 40 + ac] = *(const uint4*)&W[(size_t)(n0 + ar) * Kp + k0 + ac];
        __syncthreads();

        bf16x8 af[4], bfr[2];
#pragma unroll
        for (int i = 0; i < 4; ++i)
            af[i] = *(const bf16x8*)&As[(wm + i * 16 + lr) * 40 + quad * 8];
#pragma unroll
        for (int j = 0; j < 2; ++j)
            bfr[j] = *(const bf16x8*)&Bs[(wn + j * 16 + lr) * 40 + quad * 8];
#pragma unroll
        for (int i = 0; i < 4; ++i)
#pragma unroll
            for (int j = 0; j < 2; ++j)
                acc[i][j] = __builtin_amdgcn_mfma_f32_16x16x32_bf16(af[i], bfr[j], acc[i][j], 0, 0, 0);
    }

#pragma unroll
    for (int j = 0; j < 2; ++j) {
        const int n = n0 + wn + j * 16 + lr;
        const float bv = (kz == 0 && n < Nout) ? bias[n] : 0.f;
#pragma unroll
        for (int i = 0; i < 4; ++i) {
            const int mrow = m0 + wm + i * 16 + quad * 4;
#pragma unroll
            for (int r = 0; r < 4; ++r)
                C[(size_t)(mrow + r) * ldc + n] = acc[i][j][r] + bv;
        }
    }
}

// lin10: out[b,o<10] = (U[+U2]) @ W^T + bias; 16 img x 16 k-strips per block.
__device__ void role_lin10(char* smem, int blk,
    const float* __restrict__ U, const float* __restrict__ U2, int ldu,
    const float* __restrict__ W, const float* __restrict__ bias,
    float* __restrict__ out)
{
    float* red = (float*)smem;   // [16][10][17]
    const int t = threadIdx.x;
    const int ks = t & 15;
    const int il = t >> 4;
    const int b  = blk * 16 + il;
    const float* u = U + (size_t)b * ldu;

    float acc[10];
#pragma unroll
    for (int o = 0; o < 10; ++o) acc[o] = 0.f;

    if (U2) {
        const float* u2 = U2 + (size_t)b * ldu;
        for (int i = 0; i < 31; ++i) {
            const int k = ks + i * 16;
            const float uv = u[k] + u2[k];
#pragma unroll
            for (int o = 0; o < 10; ++o) acc[o] += uv * W[o * 500 + k];
        }
        const int k = ks + 496;
        if (k < 500) {
            const float uv = u[k] + u2[k];
#pragma unroll
            for (int o = 0; o < 10; ++o) acc[o] += uv * W[o * 500 + k];
        }
    } else {
        for (int i = 0; i < 31; ++i) {
            const int k = ks + i * 16;
            const float uv = u[k];
#pragma unroll
            for (int o = 0; o < 10; ++o) acc[o] += uv * W[o * 500 + k];
        }
        const int k = ks + 496;
        if (k < 500) {
            const float uv = u[k];
#pragma unroll
            for (int o = 0; o < 10; ++o) acc[o] += uv * W[o * 500 + k];
        }
    }
#pragma unroll
    for (int o = 0; o < 10; ++o) red[(il * 10 + o) * 17 + ks] = acc[o];
    __syncthreads();
    if (t < 160) {
        const int il2 = t / 10, o = t - il2 * 10;
        float s = 0.f;
#pragma unroll
        for (int q = 0; q < 16; ++q) s += red[(il2 * 10 + o) * 17 + q];
        out[(size_t)(blk * 16 + il2) * 10 + o] = s + bias[o];
    }
}

// ============================ fused kernels ================================

__global__ __launch_bounds__(256) void k_prep(
    const float* x, const float* c1w, const float* c1b, float* h1, bf16_t* h1b,
    const float* l1c1w, bf16_t* Wb1, const float* l1c2w, bf16_t* Wb2,
    const float* c2w, float* w2p)
{
    extern __shared__ char smem[];
    const int g = blockIdx.x;
    if (g < 2704)        role_conv1(smem, g, x, c1w, c1b, h1, h1b);
    else if (g < 4824)   role_wb16v8(g - 2704, l1c1w, Wb1, 500, 8450, 8480, 512 * 1060);
    else if (g < 5144)   role_wb16v8(g - 4824, l1c2w, Wb2, 500, 1250, 1280, 512 * 160);
    else                 role_w2t(g - 5144, c2w, w2p);
}

__global__ __launch_bounds__(256) void k_stage1(
    const float* h1, const bf16_t* h1b, const bf16_t* Wb1, const float* l1c1b,
    float* u, float* up,
    const float* d1w, const float* d1b, int* e1,
    const float* w2p, const float* c2b, float* h2, bf16_t* h2b)
{
    extern __shared__ char smem[];
    const int g = blockIdx.x;
    if (g < 512)         role_gemm(smem, g, h1b, 8480, Wb1, l1c1b, u, up, 8480, 4256, 500, 512);
    else if (g < 4608)   role_conv2(smem, g - 512, h1, w2p, c2b, h2, h2b);
    else                 role_exit(smem, g - 4608, h1, 8480, 8450, d1w, d1b, e1);
}

__global__ __launch_bounds__(256) void k_stage2(
    const float* h2, const bf16_t* h2b, const bf16_t* Wb2, const float* l1c2b,
    float* v, float* vp,
    const float* d2w, const float* d2b, int* e2,
    const float* c3w, const float* c3b, float* f3,
    const float* u, const float* up, const float* l2c1w, const float* l2c1b, float* out1)
{
    extern __shared__ char smem[];
    const int g = blockIdx.x;
    if (g < 512)         role_gemm(smem, g, h2b, 1280, Wb2, l1c2b, v, vp, 1280, 640, 500, 512);
    else if (g < 1536)   role_conv3x(smem, g - 512, h2, c3w, c3b, d2w, d2b, e2, f3);
    else                 role_lin10(smem, g - 1536, u, up, 512, l2c1w, l2c1b, out1);
}

// k_tail: per block = 16 samples. lin10-2 (v/vp) -> o2loc; lin500 -> u3 LDS;
// lin10-3 (u3 LDS) -> o3loc; select + log_softmax -> out. FP per-(b,o)
// expressions identical to round 10's separate kernels.
__global__ __launch_bounds__(256) void k_tail(
    const float* __restrict__ v, const float* __restrict__ vp,
    const float* __restrict__ l2c2w, const float* __restrict__ l2c2b,
    const float* __restrict__ f3, const float* __restrict__ l1w, const float* __restrict__ l1b,
    const float* __restrict__ l2w, const float* __restrict__ l2b,
    const float* __restrict__ out1, const int* __restrict__ e1, const int* __restrict__ e2,
    float* __restrict__ out)
{
    __shared__ float fs[800];        // 16 x 50
    __shared__ float u3loc[8000];    // 16 x 500
    __shared__ float red[2720];      // 16 x 10 x 17
    __shared__ float o2loc[160];
    __shared__ float o3loc[160];

    const int t   = threadIdx.x;
    const int blk = blockIdx.x;
    const int ks  = t & 15;
    const int il  = t >> 4;

    // stage f3 for 16 images
    for (int i = t; i < 800; i += 256) fs[i] = f3[(size_t)blk * 800 + i];
    __syncthreads();

    // lin500 -> u3loc (same per-(b,o) expression as round 10's role_lin500)
    for (int im = 0; im < 16; ++im) {
        for (int o = t; o < 500; o += 256) {
            float s = 0.f;
#pragma unroll
            for (int k = 0; k < 50; ++k) s += fs[im * 50 + k] * l1w[o * 50 + k];
            u3loc[im * 500 + o] = fmaxf(s + l1b[o], 0.f);
        }
    }

    // lin10-2 from v/vp (global, ldu=512)
    {
        const float* uu  = v  + (size_t)(blk * 16 + il) * 512;
        const float* uu2 = vp + (size_t)(blk * 16 + il) * 512;
        float acc[10];
#pragma unroll
        for (int o = 0; o < 10; ++o) acc[o] = 0.f;
        for (int i = 0; i < 31; ++i) {
            const int k = ks + i * 16;
            const float uv = uu[k] + uu2[k];
#pragma unroll
            for (int o = 0; o < 10; ++o) acc[o] += uv * l2c2w[o * 500 + k];
        }
        const int k = ks + 496;
        if (k < 500) {
            const float uv = uu[k] + uu2[k];
#pragma unroll
            for (int o = 0; o < 10; ++o) acc[o] += uv * l2c2w[o * 500 + k];
        }
        __syncthreads();   // u3loc writes done; red free to use
#pragma unroll
        for (int o = 0; o < 10; ++o) red[(il * 10 + o) * 17 + ks] = acc[o];
        __syncthreads();
        if (t < 160) {
            const int il2 = t / 10, o = t - il2 * 10;
            float s = 0.f;
#pragma unroll
            for (int q = 0; q < 16; ++q) s += red[(il2 * 10 + o) * 17 + q];
            o2loc[t] = s + l2c2b[o];
        }
        __syncthreads();
    }

    // lin10-3 from u3loc (LDS, ldu=500)
    {
        const float* uu = u3loc + il * 500;
        float acc[10];
#pragma unroll
        for (int o = 0; o < 10; ++o) acc[o] = 0.f;
        for (int i = 0; i < 31; ++i) {
            const int k = ks + i * 16;
            const float uv = uu[k];
#pragma unroll
            for (int o = 0; o < 10; ++o) acc[o] += uv * l2w[o * 500 + k];
        }
        const int k = ks + 496;
        if (k < 500) {
            const float uv = uu[k];
#pragma unroll
            for (int o = 0; o < 10; ++o) acc[o] += uv * l2w[o * 500 + k];
        }
#pragma unroll
        for (int o = 0; o < 10; ++o) red[(il * 10 + o) * 17 + ks] = acc[o];
        __syncthreads();
        if (t < 160) {
            const int il2 = t / 10, o = t - il2 * 10;
            float s = 0.f;
#pragma unroll
            for (int q = 0; q < 16; ++q) s += red[(il2 * 10 + o) * 17 + q];
            o3loc[t] = s + l2b[o];
        }
        __syncthreads();
    }

    // select + log_softmax (one thread per sample)
    if (t < 16) {
        const int b = blk * 16 + t;
        float vv[10];
        if (e1[b]) {
            const float* src = out1 + (size_t)b * 10;
#pragma unroll
            for (int o = 0; o < 10; ++o) vv[o] = src[o];
        } else if (e2[b]) {
#pragma unroll
            for (int o = 0; o < 10; ++o) vv[o] = o2loc[t * 10 + o];
        } else {
#pragma unroll
            for (int o = 0; o < 10; ++o) vv[o] = o3loc[t * 10 + o];
        }
        float m = -3.4e38f;
#pragma unroll
        for (int o = 0; o < 10; ++o) m = fmaxf(m, vv[o]);
        float s = 0.f;
#pragma unroll
        for (int o = 0; o < 10; ++o) s += expf(vv[o] - m);
        const float ls = logf(s);
#pragma unroll
        for (int o = 0; o < 10; ++o) out[(size_t)b * 10 + o] = vv[o] - m - ls;
    }
}

// ---------------------------------------------------------------------------
static inline size_t align256(size_t v) { return (v + 255) & ~(size_t)255; }

extern "C" void kernel_launch(void* const* d_in, const int* in_sizes, int n_in,
                              void* d_out, int out_size, void* d_ws, size_t ws_size,
                              hipStream_t stream)
{
    const float* x     = (const float*)d_in[0];
    const float* c1w   = (const float*)d_in[1];
    const float* c1b   = (const float*)d_in[2];
    const float* c2w   = (const float*)d_in[3];
    const float* c2b   = (const float*)d_in[4];
    const float* c3w   = (const float*)d_in[5];
    const float* c3b   = (const float*)d_in[6];
    const float* l1c1w = (const float*)d_in[7];
    const float* l1c1b = (const float*)d_in[8];
    const float* l2c1w = (const float*)d_in[9];
    const float* l2c1b = (const float*)d_in[10];
    const float* l1c2w = (const float*)d_in[11];
    const float* l1c2b = (const float*)d_in[12];
    const float* l2c2w = (const float*)d_in[13];
    const float* l2c2b = (const float*)d_in[14];
    const float* l1w   = (const float*)d_in[15];
    const float* l1b   = (const float*)d_in[16];
    const float* l2w   = (const float*)d_in[17];
    const float* l2b   = (const float*)d_in[18];
    const float* d1w   = (const float*)d_in[19];
    const float* d1b   = (const float*)d_in[20];
    const float* d2w   = (const float*)d_in[21];
    const float* d2b   = (const float*)d_in[22];

    // ---- workspace layout (single chunk, B=4096)
    size_t off = 0;
    const size_t oWb1  = off; off = align256(off + (size_t)512 * 8480 * 2);
    const size_t oWb2  = off; off = align256(off + (size_t)512 * 1280 * 2);
    const size_t oW2P  = off; off = align256(off + (size_t)50 * 600 * 4);
    const size_t oOut1 = off; off = align256(off + (size_t)B_IMG * 10 * 4);
    const size_t oE1   = off; off = align256(off + (size_t)B_IMG * 4);
    const size_t oE2   = off; off = align256(off + (size_t)B_IMG * 4);
    const size_t oH1   = off; off = align256(off + (size_t)B_IMG * 8480 * 4);
    const size_t oH2   = off; off = align256(off + (size_t)B_IMG * 1280 * 4);
    const size_t oU    = off; off = align256(off + (size_t)B_IMG * 512 * 4);
    const size_t oUP   = off; off = align256(off + (size_t)B_IMG * 512 * 4);
    const size_t oF3   = off; off = align256(off + (size_t)B_IMG * 50 * 4);
    const size_t oH1B  = off; off = align256(off + (size_t)B_IMG * 8480 * 2);
    const size_t oH2B  = off; off = align256(off + (size_t)B_IMG * 1280 * 2);

    char* ws = (char*)d_ws;
    bf16_t* Wb1  = (bf16_t*)(ws + oWb1);
    bf16_t* Wb2  = (bf16_t*)(ws + oWb2);
    float*  w2p  = (float*) (ws + oW2P);
    float*  out1 = (float*) (ws + oOut1);
    int*    e1   = (int*)   (ws + oE1);
    int*    e2   = (int*)   (ws + oE2);
    float*  h1   = (float*) (ws + oH1);
    float*  h2   = (float*) (ws + oH2);
    float*  u    = (float*) (ws + oU);
    float*  up   = (float*) (ws + oUP);
    float*  f3   = (float*) (ws + oF3);
    bf16_t* h1b  = (bf16_t*)(ws + oH1B);
    bf16_t* h2b  = (bf16_t*)(ws + oH2B);
    // stage-2 gemm outputs carved from the dead h1 region
    float*  v    = h1;                          // 4096*512 f32
    float*  vp   = h1 + (size_t)B_IMG * 512;    // 4096*512 f32

    float* out = (float*)d_out;

    // P: conv1 (+h1b mirror) + weight conversions (all independent)
    k_prep<<<5262, 256, 2048, stream>>>(x, c1w, c1b, h1, h1b,
                                        l1c1w, Wb1, l1c2w, Wb2, c2w, w2p);
    // A: gemm1(h1b) | conv2(+h2b) | exit1  (consume h1/h1b); LDS 24832
    k_stage1<<<8704, 256, 24832, stream>>>(h1, h1b, Wb1, l1c1b, u, up,
                                           d1w, d1b, e1, w2p, c2b, h2, h2b);
    // C: gemm2(h2b) | conv3+exit2 | lin10-1  (consume h2/h2b, stage1-u)
    k_stage2<<<1792, 256, 20000, stream>>>(h2, h2b, Wb2, l1c2b, v, vp, d2w, d2b, e2,
                                           c3w, c3b, f3, u, up, l2c1w, l2c1b, out1);
    // T: lin10-2 | lin500 | lin10-3 | select  (per-16-sample blocks)
    k_tail<<<256, 256, 0, stream>>>(v, vp, l2c2w, l2c2b, f3, l1w, l1b, l2w, l2b,
                                    out1, e1, e2, out);

    (void)in_sizes; (void)n_in; (void)out_size; (void)ws_size;
}